// Round 15
// baseline (256.308 us; speedup 1.0000x reference)
//
#include <hip/hip_runtime.h>
#include <math.h>

#define B_  16
#define H_  512
#define L_  2048
#define N2_ 32
#define NC_ 16
#define LC_ 128   // L_/NC_

typedef __attribute__((ext_vector_type(8))) short short8;
typedef __attribute__((ext_vector_type(4))) float f32x4;

__device__ __forceinline__ short f2bf(float x) {
    unsigned u = __builtin_bit_cast(unsigned, x);
    u += 0x7fffu + ((u >> 16) & 1u);           // round-to-nearest-even
    return (short)(u >> 16);
}
__device__ __forceinline__ float bf2f(unsigned short s) {
    unsigned u = ((unsigned)s) << 16;
    return __builtin_bit_cast(float, u);
}

// async global->LDS, 16B per lane; lds dst is wave-uniform base + lane*16
__device__ __forceinline__ void gl16(const short* g, short* l) {
    __builtin_amdgcn_global_load_lds(
        (__attribute__((address_space(1))) const void*)g,
        (__attribute__((address_space(3))) void*)l, 16, 0, 0);
}

// ---------------------------------------------------------------------------
// K0: per-(h,n) table: lambda = exp(dt*A), C' = (C_re+iC_im)*(lambda-1)/A
// ---------------------------------------------------------------------------
__global__ void k0_table(const float* __restrict__ log_dt,
                         const float* __restrict__ C_re,
                         const float* __restrict__ C_im,
                         float4* __restrict__ tab) {
    int idx = blockIdx.x * blockDim.x + threadIdx.x;   // h*N2 + n
    if (idx >= H_ * N2_) return;
    int h = idx >> 5, n = idx & 31;
    float dt = expf(log_dt[h]);
    float e  = expf(-0.5f * dt);
    float th = 3.14159265358979323846f * (float)n * dt;
    float lr = e * cosf(th), li = e * sinf(th);
    float ar = -0.5f, ai = 3.14159265358979323846f * (float)n;
    float den = ar * ar + ai * ai;
    float x = lr - 1.0f, y = li;
    float nr = (x * ar + y * ai) / den;
    float ni = (y * ar - x * ai) / den;
    float cr = C_re[idx], ci = C_im[idx];
    tab[idx] = make_float4(lr, li, cr * nr - ci * ni, cr * ni + ci * nr);
}

// ---------------------------------------------------------------------------
// T0: POW[h][m][n] = lambda_n^m, m = 0..128 (complex f32)
// ---------------------------------------------------------------------------
__global__ void t0_pow(const float4* __restrict__ tab, float2* __restrict__ POW) {
    int t = blockIdx.x * 256 + threadIdx.x;   // h*N2 + n
    if (t >= H_ * N2_) return;
    int h = t >> 5;
    float4 v = tab[t];
    float lr = v.x, li = v.y;
    float pr = 1.0f, pi = 0.0f;
    float2* base = POW + (size_t)h * 129 * N2_ + (t & 31);
    for (int m = 0; m <= 128; ++m) {
        base[(size_t)m * N2_] = make_float2(pr, pi);
        float npr = pr * lr - pi * li;
        float npi = pr * li + pi * lr;
        pr = npr; pi = npi;
    }
}

// ---------------------------------------------------------------------------
// ktab[h][m] = 2 * Re sum_n C'_n * lambda_n^m ; +D[h] at m=0 (folds D*u into
// the Toeplitz diagonal so the GELU stage never touches u).
// ---------------------------------------------------------------------------
__global__ void t_ktab(const float4* __restrict__ tab, const float2* __restrict__ POW,
                       const float* __restrict__ Dv, float* __restrict__ ktab) {
    int t = blockIdx.x * 256 + threadIdx.x;   // h*128 + m
    if (t >= H_ * 128) return;
    int h = t >> 7, m = t & 127;
    const float2* P = POW + (size_t)h * 129 * N2_ + (size_t)m * N2_;
    const float4* tb = tab + h * N2_;
    float s = 0.0f;
    for (int n = 0; n < N2_; ++n) {
        float2 p = P[n];
        float4 v = tb[n];
        s += v.z * p.x - v.w * p.y;
    }
    ktab[t] = 2.0f * s + (m == 0 ? Dv[h] : 0.0f);
}

// ---------------------------------------------------------------------------
// T1: fill Psw (pre-swizzled [h][g16][n192][8] bf16) and Vsw ([h][g8][l128][8]).
// ---------------------------------------------------------------------------
__global__ void __launch_bounds__(256)
t1_fill(const float4* __restrict__ tab, const float2* __restrict__ POW,
        const float* __restrict__ ktab, short* __restrict__ Psw,
        short* __restrict__ Vsw) {
    int t = blockIdx.x * 256 + threadIdx.x;
    int sub = t & 7;
    int rowg = t >> 3;
    int h = rowg / 320, row = rowg % 320;
    if (row < 192) {
        short8 s0, s1;
        if (row < 128) {
            int l = row;
#pragma unroll
            for (int mm = 0; mm < 8; ++mm) {
                int m0 = sub * 16 + mm, m1 = m0 + 8;
                s0[mm] = (m0 <= l) ? f2bf(ktab[h * 128 + (l - m0)]) : (short)0;
                s1[mm] = (m1 <= l) ? f2bf(ktab[h * 128 + (l - m1)]) : (short)0;
            }
        } else {
            int j = row - 128, nn = j >> 1, part = j & 1;
            const float2* P = POW + (size_t)h * 129 * N2_ + nn;
#pragma unroll
            for (int mm = 0; mm < 8; ++mm) {
                int m0 = sub * 16 + mm, m1 = m0 + 8;
                float2 p0 = P[(size_t)(127 - m0) * N2_];
                float2 p1 = P[(size_t)(127 - m1) * N2_];
                s0[mm] = f2bf(part ? p0.y : p0.x);
                s1[mm] = f2bf(part ? p1.y : p1.x);
            }
        }
        *(short8*)(Psw + ((size_t)(h * 16 + sub * 2 + 0) * 192 + row) * 8) = s0;
        *(short8*)(Psw + ((size_t)(h * 16 + sub * 2 + 1) * 192 + row) * 8) = s1;
    } else {
        int l = row - 192;
        const float2* P = POW + (size_t)h * 129 * N2_ + (size_t)(l + 1) * N2_;
        const float4* tb = tab + h * N2_;
        short8 s;
#pragma unroll
        for (int jj = 0; jj < 8; ++jj) {
            int j = sub * 8 + jj, nn = j >> 1;
            float2 p = P[nn];
            float4 cv = tb[nn];
            float re = cv.z * p.x - cv.w * p.y;
            float im = cv.z * p.y + cv.w * p.x;
            s[jj] = f2bf((j & 1) ? -2.0f * im : 2.0f * re);
        }
        *(short8*)(Vsw + ((size_t)(h * 8 + sub) * 128 + l) * 8) = s;
    }
}

// ---------------------------------------------------------------------------
// conv_mfma v3: ONE block per h (512 thr, 8 waves): Out(256x192) =
// U(256x128) @ P_h^T. Y epilogue staged through LDS then written coalesced.
// E (cols 128..191) written direct (64B segments).
// ---------------------------------------------------------------------------
__global__ void __launch_bounds__(512)
conv_mfma(const float* __restrict__ u, const short* __restrict__ Psw,
          float* __restrict__ E, short* __restrict__ Ybuf) {
    __shared__ char smem[65536];
    short* Ps = (short*)smem;                  // [16][192][8] 48K (conv)
    short* As = (short*)(smem + 49152);        // [4][256][8]  16K (conv)
    short* Ys = (short*)smem;                  // [256][128]   64K (post-conv)
    int h = blockIdx.x;
    int tid = threadIdx.x;
    {
        const short8* Pg = (const short8*)(Psw + (size_t)h * 24576);
        short8* PsV = (short8*)Ps;
#pragma unroll
        for (int j = 0; j < 6; ++j) PsV[tid + j * 512] = Pg[tid + j * 512];
    }
    int row = tid >> 1, half = tid & 1;      // row 0..255
    int b0 = row >> 4, c0 = row & 15;
    const float* up = u + ((size_t)(b0 * H_ + h)) * L_ + (size_t)c0 * LC_ + half * 16;
    short8* AsV = (short8*)As;

    int lane = tid & 63, wave = tid >> 6;    // 8 waves
    int wm = wave >> 1, wn = wave & 1;       // 4M x 2N
    int lrow = lane & 15, lk = lane >> 4;
    const short8* AsF = (const short8*)As;
    const short8* PsF = (const short8*)Ps;

    f32x4 acc[4][6] = {};
    float4 fv0 = *(const float4*)(up + 0);
    float4 fv1 = *(const float4*)(up + 4);
    float4 fv2 = *(const float4*)(up + 8);
    float4 fv3 = *(const float4*)(up + 12);
    for (int ks = 0; ks < 4; ++ks) {
        __syncthreads();
        short8 s0, s1;
        s0[0] = f2bf(fv0.x); s0[1] = f2bf(fv0.y); s0[2] = f2bf(fv0.z); s0[3] = f2bf(fv0.w);
        s0[4] = f2bf(fv1.x); s0[5] = f2bf(fv1.y); s0[6] = f2bf(fv1.z); s0[7] = f2bf(fv1.w);
        s1[0] = f2bf(fv2.x); s1[1] = f2bf(fv2.y); s1[2] = f2bf(fv2.z); s1[3] = f2bf(fv2.w);
        s1[4] = f2bf(fv3.x); s1[5] = f2bf(fv3.y); s1[6] = f2bf(fv3.z); s1[7] = f2bf(fv3.w);
        AsV[(half * 2 + 0) * 256 + row] = s0;
        AsV[(half * 2 + 1) * 256 + row] = s1;
        __syncthreads();
        if (ks < 3) {
            const float* nx = up + (ks + 1) * 32;
            fv0 = *(const float4*)(nx + 0);
            fv1 = *(const float4*)(nx + 4);
            fv2 = *(const float4*)(nx + 8);
            fv3 = *(const float4*)(nx + 12);
        }
        short8 af[4], bfr[6];
#pragma unroll
        for (int m = 0; m < 4; ++m)
            af[m] = AsF[lk * 256 + wm * 64 + m * 16 + lrow];
#pragma unroll
        for (int n = 0; n < 6; ++n)
            bfr[n] = PsF[(ks * 4 + lk) * 192 + wn * 96 + n * 16 + lrow];
#pragma unroll
        for (int m = 0; m < 4; ++m)
#pragma unroll
            for (int n = 0; n < 6; ++n)
                acc[m][n] = __builtin_amdgcn_mfma_f32_16x16x32_bf16(
                    af[m], bfr[n], acc[m][n], 0, 0, 0);
    }
    __syncthreads();   // conv LDS reads done; Ps/As reusable as Ys

    // Y fragments -> LDS stage; E fragments -> global direct
#pragma unroll
    for (int nf = 0; nf < 6; ++nf) {
        int col = wn * 96 + nf * 16 + lrow;
#pragma unroll
        for (int mf = 0; mf < 4; ++mf) {
            int rb = wm * 64 + mf * 16 + lk * 4;
#pragma unroll
            for (int r = 0; r < 4; ++r) {
                int Rr = rb + r;
                float vv = acc[mf][nf][r];
                if (col < 128) {
                    Ys[Rr * 128 + col] = f2bf(vv);
                } else {
                    int bb = Rr >> 4, cc = Rr & 15;
                    E[((size_t)(bb * H_ + h) * NC_ + cc) * 64 + (col - 128)] = vv;
                }
            }
        }
    }
    __syncthreads();

    // coalesced copy-out: 16-lane group writes one full 256B Ybuf row
    const short8* YsV = (const short8*)Ys;
#pragma unroll
    for (int it = 0; it < 8; ++it) {
        int sidx = it * 512 + tid;          // short8 index, 0..4095
        int rr = sidx >> 4;                 // local row 0..255
        int colq = sidx & 15;               // short8 within row
        int bb = rr >> 4, cc = rr & 15;
        *(short8*)(Ybuf + ((size_t)(bb * H_ + h)) * L_ + (size_t)cc * LC_ + colq * 8)
            = YsV[sidx];
    }
}

// ---------------------------------------------------------------------------
// K2: per-(b,h,n) serial scan over chunks (exclusive -> S at chunk start).
// ---------------------------------------------------------------------------
__global__ void k2_scan(const float* __restrict__ log_dt, float2* __restrict__ ES) {
    int t = blockIdx.x * 256 + threadIdx.x;
    if (t >= B_ * H_ * N2_) return;
    int n  = t & 31;
    int h  = (t >> 5) & (H_ - 1);
    int bh = t >> 5;
    float dt = expf(log_dt[h]);
    float e  = expf(-0.5f * dt * (float)LC_);
    float th = 3.14159265358979323846f * (float)n * dt * (float)LC_;
    float Lr = e * cosf(th), Li = e * sinf(th);
    float cr = 0.0f, ci = 0.0f;
    float2* base = ES + (size_t)bh * NC_ * N2_ + n;
#pragma unroll
    for (int c = 0; c < NC_; ++c) {
        float2 Ev = base[(size_t)c * N2_];
        base[(size_t)c * N2_] = make_float2(cr, ci);
        float ncr = fmaf(Lr, cr, fmaf(-Li, ci, Ev.x));
        float nci = fmaf(Lr, ci, fmaf(Li, cr, Ev.y));
        cr = ncr; ci = nci;
    }
}

// ---------------------------------------------------------------------------
// dcarry_mfma v2: per (h, mh): Carry(128x128) = S(128x64) @ V_h^T via MFMA.
// Carry fragments staged in LDS (aliasing dead Sa/Vb), then fused coalesced
// epilogue: gbf = bf16(GELU(Ybuf + carry)) in full short8 rows.
// ---------------------------------------------------------------------------
__global__ void __launch_bounds__(256)
dcarry_mfma(const float* __restrict__ ES, const short* __restrict__ Vsw,
            const short* __restrict__ Ybuf, short* __restrict__ gbf) {
    __shared__ char smem[32768];
    short* Sa = (short*)smem;             // [8][128][8] 16 KB
    short* Vb = (short*)(smem + 16384);   // [8][128][8] 16 KB
    short* Ys = (short*)smem;             // [128][128]  32 KB (post-MFMA)
    int h = blockIdx.x, mh = blockIdx.y;
    int tid = threadIdx.x;
    {
        const short8* Vg = (const short8*)(Vsw + (size_t)h * 8192);
        short8* VbV = (short8*)Vb;
#pragma unroll
        for (int j = 0; j < 4; ++j) VbV[tid + j * 256] = Vg[tid + j * 256];
    }
    int row = tid >> 1, half = tid & 1;
    int R = mh * 128 + row, b = R >> 4, c = R & 15;
    {
        const float* sp = ES + ((size_t)(b * H_ + h) * NC_ + c) * 64 + half * 32;
        short8* SaV = (short8*)Sa;
#pragma unroll
        for (int gg = 0; gg < 4; ++gg) {
            float4 f0 = *(const float4*)(sp + gg * 8);
            float4 f1 = *(const float4*)(sp + gg * 8 + 4);
            short8 s;
            s[0] = f2bf(f0.x); s[1] = f2bf(f0.y); s[2] = f2bf(f0.z); s[3] = f2bf(f0.w);
            s[4] = f2bf(f1.x); s[5] = f2bf(f1.y); s[6] = f2bf(f1.z); s[7] = f2bf(f1.w);
            SaV[(half * 4 + gg) * 128 + row] = s;
        }
    }
    __syncthreads();
    int lane = tid & 63, wave = tid >> 6;
    int wm = wave >> 1, wn = wave & 1;
    int lrow = lane & 15, lk = lane >> 4;
    const short8* SaF = (const short8*)Sa;
    const short8* VbF = (const short8*)Vb;
    f32x4 acc[4][4] = {};
#pragma unroll
    for (int ks = 0; ks < 2; ++ks) {
        int g = ks * 4 + lk;
        short8 af[4], bf[4];
#pragma unroll
        for (int m = 0; m < 4; ++m)
            af[m] = SaF[g * 128 + wm * 64 + m * 16 + lrow];
#pragma unroll
        for (int n = 0; n < 4; ++n)
            bf[n] = VbF[g * 128 + wn * 64 + n * 16 + lrow];
#pragma unroll
        for (int m = 0; m < 4; ++m)
#pragma unroll
            for (int n = 0; n < 4; ++n)
                acc[m][n] = __builtin_amdgcn_mfma_f32_16x16x32_bf16(
                    af[m], bf[n], acc[m][n], 0, 0, 0);
    }
    __syncthreads();   // Sa/Vb reads done -> reuse as Ys

    // carry fragments -> LDS stage (bf16, same precision as before)
#pragma unroll
    for (int nf = 0; nf < 4; ++nf) {
        int l = wn * 64 + nf * 16 + lrow;
#pragma unroll
        for (int mf = 0; mf < 4; ++mf) {
            int rb = wm * 64 + mf * 16 + lk * 4;
#pragma unroll
            for (int r = 0; r < 4; ++r)
                Ys[(rb + r) * 128 + l] = f2bf(acc[mf][nf][r]);
        }
    }
    __syncthreads();

    // fused coalesced epilogue: gbf = bf16(GELU(Ybuf + carry)), short8 rows
    const short8* YsV = (const short8*)Ys;
#pragma unroll
    for (int it = 0; it < 8; ++it) {
        int sidx = it * 256 + tid;          // 0..2047
        int rr = sidx >> 4;                 // local row 0..127
        int colq = sidx & 15;
        int Rr = mh * 128 + rr, bb = Rr >> 4, cc = Rr & 15;
        size_t gaddr = ((size_t)(bb * H_ + h)) * L_ + (size_t)cc * LC_ + colq * 8;
        short8 yv = *(const short8*)(Ybuf + gaddr);
        short8 cv = YsV[sidx];
        short8 o;
#pragma unroll
        for (int j = 0; j < 8; ++j) {
            float y = bf2f((unsigned short)yv[j]) + bf2f((unsigned short)cv[j]);
            o[j] = f2bf(0.5f * y * (1.0f + erff(y * 0.70710678118654752f)));
        }
        *(short8*)(gbf + gaddr) = o;
    }
}

// ---------------------------------------------------------------------------
// W transpose + f32->bf16: Wt[n][k] = bf16(W[k][n])
// ---------------------------------------------------------------------------
__global__ void __launch_bounds__(256)
wtrans(const float* __restrict__ W, short* __restrict__ Wt, int K, int N) {
    __shared__ short tile[32][33];
    int bk = blockIdx.x * 32, bn = blockIdx.y * 32;
    int tx = threadIdx.x & 31, ty = threadIdx.x >> 5;   // ty 0..7
#pragma unroll
    for (int i = 0; i < 4; ++i)
        tile[ty + i * 8][tx] = f2bf(W[(size_t)(bk + ty + i * 8) * N + bn + tx]);
    __syncthreads();
#pragma unroll
    for (int i = 0; i < 4; ++i)
        Wt[(size_t)(bn + ty + i * 8) * K + bk + tx] = tile[tx][ty + i * 8];
}

// ---------------------------------------------------------------------------
// bf16 MFMA GEMM v6 = m97/T3-minimum structure + XCD row-panel grid:
// 256 thr / 4 waves / 4x4 acc / 128x128 tile / BK=32.
// LDS [2][4kblk][128row][8] per operand (32 KB total), staged via
// global_load_lds width=16 (wave-uniform dst = base + lane*16, verified:
// thread slot (kb,r) = (tid>>7, tid&127) and (+2 kblk)). One barrier per
// K-step (its vmcnt(0) drain completes the t+1 prefetch). Scattered 16B
// global reads are L2-absorbed (4 kblk pieces of each row's 64B line are
// consumed by 4 waves of the same block); HBM fetch stays ~33MB thanks to
// the row-panel grid (r9: XCD = row-panel%8 -> A-panel L2 locality).
// ---------------------------------------------------------------------------
template<bool TANH, bool OUTBF>
__global__ void __launch_bounds__(256)
gemm_mfma(const short* __restrict__ A, const short* __restrict__ Bt,
          const float* __restrict__ bias, void* __restrict__ Cout,
          int M, int N, int K) {
    __shared__ short As[2][4 * 128 * 8];   // 8 KB per buf
    __shared__ short Bs[2][4 * 128 * 8];
    int tid  = threadIdx.x;
    int lane = tid & 63;
    int wave = tid >> 6;                 // 0..3
    int wm = wave >> 1, wn = wave & 1;   // 2M x 2N, wave tile 64x64
    int lrow = lane & 15, lk = lane >> 4;
    int row0 = blockIdx.x * 128, col0 = blockIdx.y * 128;

    // staging map: thread -> slots (kb, r) and (kb+2, r); r = tid&127, kb = tid>>7
    int sr = tid & 127, kb = tid >> 7;
    const short* Ag0 = A  + (size_t)(row0 + sr) * K + kb * 8;
    const short* Ag1 = A  + (size_t)(row0 + sr) * K + (kb + 2) * 8;
    const short* Bg0 = Bt + (size_t)(col0 + sr) * K + kb * 8;
    const short* Bg1 = Bt + (size_t)(col0 + sr) * K + (kb + 2) * 8;
    int so0 = (kb * 128 + sr) * 8;
    int so1 = ((kb + 2) * 128 + sr) * 8;

    f32x4 acc[4][4] = {};
    const int NT = K >> 5;

    // prologue: stage tile 0 -> buf 0
    gl16(Ag0, &As[0][so0]);
    gl16(Ag1, &As[0][so1]);
    gl16(Bg0, &Bs[0][so0]);
    gl16(Bg1, &Bs[0][so1]);
    __syncthreads();

    int cur = 0;
    for (int t = 0; t < NT; ++t) {
        if (t + 1 < NT) {
            int ko = (t + 1) << 5;
            gl16(Ag0 + ko, &As[cur ^ 1][so0]);
            gl16(Ag1 + ko, &As[cur ^ 1][so1]);
            gl16(Bg0 + ko, &Bs[cur ^ 1][so0]);
            gl16(Bg1 + ko, &Bs[cur ^ 1][so1]);
        }
        short8 af[4], bf[4];
#pragma unroll
        for (int m = 0; m < 4; ++m)
            af[m] = *(const short8*)&As[cur][(lk * 128 + wm * 64 + m * 16 + lrow) * 8];
#pragma unroll
        for (int n = 0; n < 4; ++n)
            bf[n] = *(const short8*)&Bs[cur][(lk * 128 + wn * 64 + n * 16 + lrow) * 8];
#pragma unroll
        for (int m = 0; m < 4; ++m)
#pragma unroll
            for (int n = 0; n < 4; ++n)
                acc[m][n] = __builtin_amdgcn_mfma_f32_16x16x32_bf16(
                    af[m], bf[n], acc[m][n], 0, 0, 0);
        __syncthreads();   // drains vmcnt(0): t+1 stage complete
        cur ^= 1;
    }

    // epilogue: C/D layout col=lane&15, row=(lane>>4)*4+reg
#pragma unroll
    for (int n = 0; n < 4; ++n) {
        int col = col0 + wn * 64 + n * 16 + lrow;
        float bb = bias[col];
#pragma unroll
        for (int m = 0; m < 4; ++m) {
            int rowb = row0 + wm * 64 + m * 16 + lk * 4;
#pragma unroll
            for (int r = 0; r < 4; ++r) {
                float v = acc[m][n][r] + bb;
                if (TANH) v = tanhf(v);
                if (OUTBF) ((short*)Cout)[(size_t)(rowb + r) * N + col] = f2bf(v);
                else       ((float*)Cout)[(size_t)(rowb + r) * N + col] = v;
            }
        }
    }
}

// ---------------------------------------------------------------------------
extern "C" void kernel_launch(void* const* d_in, const int* in_sizes, int n_in,
                              void* d_out, int out_size, void* d_ws, size_t ws_size,
                              hipStream_t stream) {
    const float* u     = (const float*)d_in[0];
    const float* D     = (const float*)d_in[1];
    const float* logdt = (const float*)d_in[2];
    const float* C_re  = (const float*)d_in[3];
    const float* C_im  = (const float*)d_in[4];
    const float* W1    = (const float*)d_in[5];
    const float* b1    = (const float*)d_in[6];
    const float* W2    = (const float*)d_in[7];
    const float* b2    = (const float*)d_in[8];
    float* out = (float*)d_out;

    char* p = (char*)d_ws;
    float4* tab = (float4*)p;            p += 262144;      // H*N2*16
    char* regionA = p;                   p += 33554432;    // POW+ktab, later Ybuf
    float2* POW  = (float2*)regionA;                       // 512*129*32*8
    float*  ktab = (float*)(regionA + 16908288);           // 512*128*4
    short*  Ybuf = (short*)regionA;                        // B*H*L*2 = 32 MB (b,h,l)
    short* Psw = (short*)p;              p += 25165824;    // 512*192*128*2
    short* Vsw = (short*)p;              p += 8388608;     // 512*128*64*2
    float* E   = (float*)p;              p += 33554432;    // 8192*16*64*4
    short* gbf = (short*)p;              p += 33554432;    // B*H*L*2
    short* tb  = (short*)p;              p += 16777216;    // 8192*1024*2
    short* w1t = (short*)p;              p += 4194304;
    short* w2t = (short*)p;

    k0_table<<<H_ * N2_ / 256, 256, 0, stream>>>(logdt, C_re, C_im, tab);
    t0_pow  <<<H_ * N2_ / 256, 256, 0, stream>>>(tab, POW);
    t_ktab  <<<H_ * 128 / 256, 256, 0, stream>>>(tab, POW, D, ktab);
    t1_fill <<<H_ * 320 * 8 / 256, 256, 0, stream>>>(tab, POW, ktab, Psw, Vsw);
    wtrans  <<<dim3(L_ / 32, 2 * H_ / 32), 256, 0, stream>>>(W1, w1t, L_, 2 * H_);
    wtrans  <<<dim3(2 * H_ / 32, H_ / 32), 256, 0, stream>>>(W2, w2t, 2 * H_, H_);

    conv_mfma  <<<H_, 512, 0, stream>>>(u, Psw, E, Ybuf);
    k2_scan    <<<B_ * H_ * N2_ / 256, 256, 0, stream>>>(logdt, (float2*)E);
    dcarry_mfma<<<dim3(H_, 2), 256, 0, stream>>>(E, Vsw, Ybuf, gbf);

    gemm_mfma<true, true ><<<dim3(B_ * H_ / 128, 2 * H_ / 128), 256, 0, stream>>>(
        gbf, w1t, b1, tb, B_ * H_, 2 * H_, L_);
    gemm_mfma<false, false><<<dim3(B_ * H_ / 128, H_ / 128), 256, 0, stream>>>(
        tb, w2t, b2, out, B_ * H_, H_, 2 * H_);
}

// Round 16
// 208.248 us; speedup vs baseline: 1.2308x; 1.2308x over previous
//
#include <hip/hip_runtime.h>
#include <math.h>

#define B_  16
#define H_  512
#define L_  2048
#define N2_ 32
#define NC_ 16
#define LC_ 128   // L_/NC_

typedef __attribute__((ext_vector_type(8))) short short8;
typedef __attribute__((ext_vector_type(4))) float f32x4;

__device__ __forceinline__ short f2bf(float x) {
    unsigned u = __builtin_bit_cast(unsigned, x);
    u += 0x7fffu + ((u >> 16) & 1u);           // round-to-nearest-even
    return (short)(u >> 16);
}
__device__ __forceinline__ float bf2f(unsigned short s) {
    unsigned u = ((unsigned)s) << 16;
    return __builtin_bit_cast(float, u);
}

// ---------------------------------------------------------------------------
// K0: per-(h,n) table: lambda = exp(dt*A), C' = (C_re+iC_im)*(lambda-1)/A
// ---------------------------------------------------------------------------
__global__ void k0_table(const float* __restrict__ log_dt,
                         const float* __restrict__ C_re,
                         const float* __restrict__ C_im,
                         float4* __restrict__ tab) {
    int idx = blockIdx.x * blockDim.x + threadIdx.x;   // h*N2 + n
    if (idx >= H_ * N2_) return;
    int h = idx >> 5, n = idx & 31;
    float dt = expf(log_dt[h]);
    float e  = expf(-0.5f * dt);
    float th = 3.14159265358979323846f * (float)n * dt;
    float lr = e * cosf(th), li = e * sinf(th);
    float ar = -0.5f, ai = 3.14159265358979323846f * (float)n;
    float den = ar * ar + ai * ai;
    float x = lr - 1.0f, y = li;
    float nr = (x * ar + y * ai) / den;
    float ni = (y * ar - x * ai) / den;
    float cr = C_re[idx], ci = C_im[idx];
    tab[idx] = make_float4(lr, li, cr * nr - ci * ni, cr * ni + ci * nr);
}

// ---------------------------------------------------------------------------
// T0: POW[h][m][n] = lambda_n^m, m = 0..128 (complex f32)
// ---------------------------------------------------------------------------
__global__ void t0_pow(const float4* __restrict__ tab, float2* __restrict__ POW) {
    int t = blockIdx.x * 256 + threadIdx.x;   // h*N2 + n
    if (t >= H_ * N2_) return;
    int h = t >> 5;
    float4 v = tab[t];
    float lr = v.x, li = v.y;
    float pr = 1.0f, pi = 0.0f;
    float2* base = POW + (size_t)h * 129 * N2_ + (t & 31);
    for (int m = 0; m <= 128; ++m) {
        base[(size_t)m * N2_] = make_float2(pr, pi);
        float npr = pr * lr - pi * li;
        float npi = pr * li + pi * lr;
        pr = npr; pi = npi;
    }
}

// ---------------------------------------------------------------------------
// ktab[h][m] = 2 * Re sum_n C'_n * lambda_n^m ; +D[h] at m=0 (folds D*u into
// the Toeplitz diagonal so the GELU stage never touches u).
// ---------------------------------------------------------------------------
__global__ void t_ktab(const float4* __restrict__ tab, const float2* __restrict__ POW,
                       const float* __restrict__ Dv, float* __restrict__ ktab) {
    int t = blockIdx.x * 256 + threadIdx.x;   // h*128 + m
    if (t >= H_ * 128) return;
    int h = t >> 7, m = t & 127;
    const float2* P = POW + (size_t)h * 129 * N2_ + (size_t)m * N2_;
    const float4* tb = tab + h * N2_;
    float s = 0.0f;
    for (int n = 0; n < N2_; ++n) {
        float2 p = P[n];
        float4 v = tb[n];
        s += v.z * p.x - v.w * p.y;
    }
    ktab[t] = 2.0f * s + (m == 0 ? Dv[h] : 0.0f);
}

// ---------------------------------------------------------------------------
// T1: fill Psw (pre-swizzled [h][g16][n192][8] bf16) and Vsw ([h][g8][l128][8]).
// ---------------------------------------------------------------------------
__global__ void __launch_bounds__(256)
t1_fill(const float4* __restrict__ tab, const float2* __restrict__ POW,
        const float* __restrict__ ktab, short* __restrict__ Psw,
        short* __restrict__ Vsw) {
    int t = blockIdx.x * 256 + threadIdx.x;
    int sub = t & 7;
    int rowg = t >> 3;
    int h = rowg / 320, row = rowg % 320;
    if (row < 192) {
        short8 s0, s1;
        if (row < 128) {
            int l = row;
#pragma unroll
            for (int mm = 0; mm < 8; ++mm) {
                int m0 = sub * 16 + mm, m1 = m0 + 8;
                s0[mm] = (m0 <= l) ? f2bf(ktab[h * 128 + (l - m0)]) : (short)0;
                s1[mm] = (m1 <= l) ? f2bf(ktab[h * 128 + (l - m1)]) : (short)0;
            }
        } else {
            int j = row - 128, nn = j >> 1, part = j & 1;
            const float2* P = POW + (size_t)h * 129 * N2_ + nn;
#pragma unroll
            for (int mm = 0; mm < 8; ++mm) {
                int m0 = sub * 16 + mm, m1 = m0 + 8;
                float2 p0 = P[(size_t)(127 - m0) * N2_];
                float2 p1 = P[(size_t)(127 - m1) * N2_];
                s0[mm] = f2bf(part ? p0.y : p0.x);
                s1[mm] = f2bf(part ? p1.y : p1.x);
            }
        }
        *(short8*)(Psw + ((size_t)(h * 16 + sub * 2 + 0) * 192 + row) * 8) = s0;
        *(short8*)(Psw + ((size_t)(h * 16 + sub * 2 + 1) * 192 + row) * 8) = s1;
    } else {
        int l = row - 192;
        const float2* P = POW + (size_t)h * 129 * N2_ + (size_t)(l + 1) * N2_;
        const float4* tb = tab + h * N2_;
        short8 s;
#pragma unroll
        for (int jj = 0; jj < 8; ++jj) {
            int j = sub * 8 + jj, nn = j >> 1;
            float2 p = P[nn];
            float4 cv = tb[nn];
            float re = cv.z * p.x - cv.w * p.y;
            float im = cv.z * p.y + cv.w * p.x;
            s[jj] = f2bf((j & 1) ? -2.0f * im : 2.0f * re);
        }
        *(short8*)(Vsw + ((size_t)(h * 8 + sub) * 128 + l) * 8) = s;
    }
}

// ---------------------------------------------------------------------------
// conv_mfma v3: ONE block per h (512 thr, 8 waves): Out(256x192) =
// U(256x128) @ P_h^T. Y epilogue staged through LDS then written coalesced.
// E (cols 128..191) written direct (64B segments).
// ---------------------------------------------------------------------------
__global__ void __launch_bounds__(512)
conv_mfma(const float* __restrict__ u, const short* __restrict__ Psw,
          float* __restrict__ E, short* __restrict__ Ybuf) {
    __shared__ char smem[65536];
    short* Ps = (short*)smem;                  // [16][192][8] 48K (conv)
    short* As = (short*)(smem + 49152);        // [4][256][8]  16K (conv)
    short* Ys = (short*)smem;                  // [256][128]   64K (post-conv)
    int h = blockIdx.x;
    int tid = threadIdx.x;
    {
        const short8* Pg = (const short8*)(Psw + (size_t)h * 24576);
        short8* PsV = (short8*)Ps;
#pragma unroll
        for (int j = 0; j < 6; ++j) PsV[tid + j * 512] = Pg[tid + j * 512];
    }
    int row = tid >> 1, half = tid & 1;      // row 0..255
    int b0 = row >> 4, c0 = row & 15;
    const float* up = u + ((size_t)(b0 * H_ + h)) * L_ + (size_t)c0 * LC_ + half * 16;
    short8* AsV = (short8*)As;

    int lane = tid & 63, wave = tid >> 6;    // 8 waves
    int wm = wave >> 1, wn = wave & 1;       // 4M x 2N
    int lrow = lane & 15, lk = lane >> 4;
    const short8* AsF = (const short8*)As;
    const short8* PsF = (const short8*)Ps;

    f32x4 acc[4][6] = {};
    float4 fv0 = *(const float4*)(up + 0);
    float4 fv1 = *(const float4*)(up + 4);
    float4 fv2 = *(const float4*)(up + 8);
    float4 fv3 = *(const float4*)(up + 12);
    for (int ks = 0; ks < 4; ++ks) {
        __syncthreads();
        short8 s0, s1;
        s0[0] = f2bf(fv0.x); s0[1] = f2bf(fv0.y); s0[2] = f2bf(fv0.z); s0[3] = f2bf(fv0.w);
        s0[4] = f2bf(fv1.x); s0[5] = f2bf(fv1.y); s0[6] = f2bf(fv1.z); s0[7] = f2bf(fv1.w);
        s1[0] = f2bf(fv2.x); s1[1] = f2bf(fv2.y); s1[2] = f2bf(fv2.z); s1[3] = f2bf(fv2.w);
        s1[4] = f2bf(fv3.x); s1[5] = f2bf(fv3.y); s1[6] = f2bf(fv3.z); s1[7] = f2bf(fv3.w);
        AsV[(half * 2 + 0) * 256 + row] = s0;
        AsV[(half * 2 + 1) * 256 + row] = s1;
        __syncthreads();
        if (ks < 3) {
            const float* nx = up + (ks + 1) * 32;
            fv0 = *(const float4*)(nx + 0);
            fv1 = *(const float4*)(nx + 4);
            fv2 = *(const float4*)(nx + 8);
            fv3 = *(const float4*)(nx + 12);
        }
        short8 af[4], bfr[6];
#pragma unroll
        for (int m = 0; m < 4; ++m)
            af[m] = AsF[lk * 256 + wm * 64 + m * 16 + lrow];
#pragma unroll
        for (int n = 0; n < 6; ++n)
            bfr[n] = PsF[(ks * 4 + lk) * 192 + wn * 96 + n * 16 + lrow];
#pragma unroll
        for (int m = 0; m < 4; ++m)
#pragma unroll
            for (int n = 0; n < 6; ++n)
                acc[m][n] = __builtin_amdgcn_mfma_f32_16x16x32_bf16(
                    af[m], bfr[n], acc[m][n], 0, 0, 0);
    }
    __syncthreads();   // conv LDS reads done; Ps/As reusable as Ys

    // Y fragments -> LDS stage; E fragments -> global direct
#pragma unroll
    for (int nf = 0; nf < 6; ++nf) {
        int col = wn * 96 + nf * 16 + lrow;
#pragma unroll
        for (int mf = 0; mf < 4; ++mf) {
            int rb = wm * 64 + mf * 16 + lk * 4;
#pragma unroll
            for (int r = 0; r < 4; ++r) {
                int Rr = rb + r;
                float vv = acc[mf][nf][r];
                if (col < 128) {
                    Ys[Rr * 128 + col] = f2bf(vv);
                } else {
                    int bb = Rr >> 4, cc = Rr & 15;
                    E[((size_t)(bb * H_ + h) * NC_ + cc) * 64 + (col - 128)] = vv;
                }
            }
        }
    }
    __syncthreads();

    // coalesced copy-out: 16-lane group writes one full 256B Ybuf row
    const short8* YsV = (const short8*)Ys;
#pragma unroll
    for (int it = 0; it < 8; ++it) {
        int sidx = it * 512 + tid;          // short8 index, 0..4095
        int rr = sidx >> 4;                 // local row 0..255
        int colq = sidx & 15;               // short8 within row
        int bb = rr >> 4, cc = rr & 15;
        *(short8*)(Ybuf + ((size_t)(bb * H_ + h)) * L_ + (size_t)cc * LC_ + colq * 8)
            = YsV[sidx];
    }
}

// ---------------------------------------------------------------------------
// K2: per-(b,h,n) serial scan over chunks (exclusive -> S at chunk start).
// ---------------------------------------------------------------------------
__global__ void k2_scan(const float* __restrict__ log_dt, float2* __restrict__ ES) {
    int t = blockIdx.x * 256 + threadIdx.x;
    if (t >= B_ * H_ * N2_) return;
    int n  = t & 31;
    int h  = (t >> 5) & (H_ - 1);
    int bh = t >> 5;
    float dt = expf(log_dt[h]);
    float e  = expf(-0.5f * dt * (float)LC_);
    float th = 3.14159265358979323846f * (float)n * dt * (float)LC_;
    float Lr = e * cosf(th), Li = e * sinf(th);
    float cr = 0.0f, ci = 0.0f;
    float2* base = ES + (size_t)bh * NC_ * N2_ + n;
#pragma unroll
    for (int c = 0; c < NC_; ++c) {
        float2 Ev = base[(size_t)c * N2_];
        base[(size_t)c * N2_] = make_float2(cr, ci);
        float ncr = fmaf(Lr, cr, fmaf(-Li, ci, Ev.x));
        float nci = fmaf(Lr, ci, fmaf(Li, cr, Ev.y));
        cr = ncr; ci = nci;
    }
}

// ---------------------------------------------------------------------------
// dcarry_mfma v2: per (h, mh): Carry(128x128) = S(128x64) @ V_h^T via MFMA.
// Carry fragments staged in LDS (aliasing dead Sa/Vb), then fused coalesced
// epilogue: gbf = bf16(GELU(Ybuf + carry)) in full short8 rows.
// ---------------------------------------------------------------------------
__global__ void __launch_bounds__(256)
dcarry_mfma(const float* __restrict__ ES, const short* __restrict__ Vsw,
            const short* __restrict__ Ybuf, short* __restrict__ gbf) {
    __shared__ char smem[32768];
    short* Sa = (short*)smem;             // [8][128][8] 16 KB
    short* Vb = (short*)(smem + 16384);   // [8][128][8] 16 KB
    short* Ys = (short*)smem;             // [128][128]  32 KB (post-MFMA)
    int h = blockIdx.x, mh = blockIdx.y;
    int tid = threadIdx.x;
    {
        const short8* Vg = (const short8*)(Vsw + (size_t)h * 8192);
        short8* VbV = (short8*)Vb;
#pragma unroll
        for (int j = 0; j < 4; ++j) VbV[tid + j * 256] = Vg[tid + j * 256];
    }
    int row = tid >> 1, half = tid & 1;
    int R = mh * 128 + row, b = R >> 4, c = R & 15;
    {
        const float* sp = ES + ((size_t)(b * H_ + h) * NC_ + c) * 64 + half * 32;
        short8* SaV = (short8*)Sa;
#pragma unroll
        for (int gg = 0; gg < 4; ++gg) {
            float4 f0 = *(const float4*)(sp + gg * 8);
            float4 f1 = *(const float4*)(sp + gg * 8 + 4);
            short8 s;
            s[0] = f2bf(f0.x); s[1] = f2bf(f0.y); s[2] = f2bf(f0.z); s[3] = f2bf(f0.w);
            s[4] = f2bf(f1.x); s[5] = f2bf(f1.y); s[6] = f2bf(f1.z); s[7] = f2bf(f1.w);
            SaV[(half * 4 + gg) * 128 + row] = s;
        }
    }
    __syncthreads();
    int lane = tid & 63, wave = tid >> 6;
    int wm = wave >> 1, wn = wave & 1;
    int lrow = lane & 15, lk = lane >> 4;
    const short8* SaF = (const short8*)Sa;
    const short8* VbF = (const short8*)Vb;
    f32x4 acc[4][4] = {};
#pragma unroll
    for (int ks = 0; ks < 2; ++ks) {
        int g = ks * 4 + lk;
        short8 af[4], bf[4];
#pragma unroll
        for (int m = 0; m < 4; ++m)
            af[m] = SaF[g * 128 + wm * 64 + m * 16 + lrow];
#pragma unroll
        for (int n = 0; n < 4; ++n)
            bf[n] = VbF[g * 128 + wn * 64 + n * 16 + lrow];
#pragma unroll
        for (int m = 0; m < 4; ++m)
#pragma unroll
            for (int n = 0; n < 4; ++n)
                acc[m][n] = __builtin_amdgcn_mfma_f32_16x16x32_bf16(
                    af[m], bf[n], acc[m][n], 0, 0, 0);
    }
    __syncthreads();   // Sa/Vb reads done -> reuse as Ys

    // carry fragments -> LDS stage (bf16, same precision as before)
#pragma unroll
    for (int nf = 0; nf < 4; ++nf) {
        int l = wn * 64 + nf * 16 + lrow;
#pragma unroll
        for (int mf = 0; mf < 4; ++mf) {
            int rb = wm * 64 + mf * 16 + lk * 4;
#pragma unroll
            for (int r = 0; r < 4; ++r)
                Ys[(rb + r) * 128 + l] = f2bf(acc[mf][nf][r]);
        }
    }
    __syncthreads();

    // fused coalesced epilogue: gbf = bf16(GELU(Ybuf + carry)), short8 rows
    const short8* YsV = (const short8*)Ys;
#pragma unroll
    for (int it = 0; it < 8; ++it) {
        int sidx = it * 256 + tid;          // 0..2047
        int rr = sidx >> 4;                 // local row 0..127
        int colq = sidx & 15;
        int Rr = mh * 128 + rr, bb = Rr >> 4, cc = Rr & 15;
        size_t gaddr = ((size_t)(bb * H_ + h)) * L_ + (size_t)cc * LC_ + colq * 8;
        short8 yv = *(const short8*)(Ybuf + gaddr);
        short8 cv = YsV[sidx];
        short8 o;
#pragma unroll
        for (int j = 0; j < 8; ++j) {
            float y = bf2f((unsigned short)yv[j]) + bf2f((unsigned short)cv[j]);
            o[j] = f2bf(0.5f * y * (1.0f + erff(y * 0.70710678118654752f)));
        }
        *(short8*)(gbf + gaddr) = o;
    }
}

// ---------------------------------------------------------------------------
// W transpose + f32->bf16: Wt[n][k] = bf16(W[k][n])
// ---------------------------------------------------------------------------
__global__ void __launch_bounds__(256)
wtrans(const float* __restrict__ W, short* __restrict__ Wt, int K, int N) {
    __shared__ short tile[32][33];
    int bk = blockIdx.x * 32, bn = blockIdx.y * 32;
    int tx = threadIdx.x & 31, ty = threadIdx.x >> 5;   // ty 0..7
#pragma unroll
    for (int i = 0; i < 4; ++i)
        tile[ty + i * 8][tx] = f2bf(W[(size_t)(bk + ty + i * 8) * N + bn + tx]);
    __syncthreads();
#pragma unroll
    for (int i = 0; i < 4; ++i)
        Wt[(size_t)(bn + ty + i * 8) * K + bk + tx] = tile[tx][ty + i * 8];
}

// ---------------------------------------------------------------------------
// bf16 MFMA GEMM v7 (4 waves / 256 thr / 128x64 tile): C = act(A@Bt^T+bias).
// Smaller tile -> GEMM1 grid 64x16 = 1024 blocks = 4 blocks/CU (was 2):
// 16 waves/CU as 4 INDEPENDENT barrier groups -> stall interleaving
// (r14 evidence: 57% idle, resources allowed 4 blocks, grid was the cap).
// Wave tile 64x32 (acc 4x2). [36]-strided LDS (r10-verified conflict-free),
// reg-staged 64B-coalesced loads, 2-deep named prefetch, 2 barriers/K-step.
// Grid dim3(M/128, N/64): XCD = row-panel%8 -> A-panel L2-resident
// (0.5MB/panel; 16x logical re-read absorbed by L2 at ~11 TB/s).
// ---------------------------------------------------------------------------
template<bool TANH, bool OUTBF>
__global__ void __launch_bounds__(256)
gemm_mfma(const short* __restrict__ A, const short* __restrict__ Bt,
          const float* __restrict__ bias, void* __restrict__ Cout,
          int M, int N, int K) {
    __shared__ short As[128 * 36 + 8];
    __shared__ short Bs[64 * 36 + 8];
    int tid  = threadIdx.x;
    int lane = tid & 63;
    int wave = tid >> 6;                 // 0..3
    int wm = wave >> 1, wn = wave & 1;   // 2M x 2N, wave tile 64x32
    int lrow = lane & 15, lk = lane >> 4;
    int row0 = blockIdx.x * 128, col0 = blockIdx.y * 64;

    int sr = tid >> 2;            // 0..63
    int sk = (tid & 3) * 8;       // k offset (shorts)
    const short* Ag0 = A  + (size_t)(row0 + sr) * K + sk;
    const short* Ag1 = A  + (size_t)(row0 + 64 + sr) * K + sk;
    const short* Bg  = Bt + (size_t)(col0 + sr) * K + sk;
    int sa0 = sr * 36 + sk;
    int sa1 = (sr + 64) * 36 + sk;
    int sb  = sr * 36 + sk;

    f32x4 acc[4][2] = {};
    const int NT = K >> 5;        // 64 (GEMM1) / 32 (GEMM2) — even

    // two statically-named prefetch sets (rule #20)
    short8 xa0 = *(const short8*)(Ag0),      xa1 = *(const short8*)(Ag1);
    short8 xb  = *(const short8*)(Bg);
    short8 ya0 = *(const short8*)(Ag0 + 32), ya1 = *(const short8*)(Ag1 + 32);
    short8 yb  = *(const short8*)(Bg + 32);

    auto gstep = [&](short8& A0, short8& A1, short8& Bv, int tnext) {
        __syncthreads();
        *(short8*)&As[sa0] = A0;
        *(short8*)&As[sa1] = A1;
        *(short8*)&Bs[sb]  = Bv;
        __syncthreads();
        if (tnext < NT) {
            int ko = tnext << 5;
            A0 = *(const short8*)(Ag0 + ko);
            A1 = *(const short8*)(Ag1 + ko);
            Bv = *(const short8*)(Bg + ko);
        }
        short8 af[4], bf[2];
#pragma unroll
        for (int m = 0; m < 4; ++m)
            af[m] = *(const short8*)&As[(wm * 64 + m * 16 + lrow) * 36 + lk * 8];
#pragma unroll
        for (int n = 0; n < 2; ++n)
            bf[n] = *(const short8*)&Bs[(wn * 32 + n * 16 + lrow) * 36 + lk * 8];
#pragma unroll
        for (int m = 0; m < 4; ++m)
#pragma unroll
            for (int n = 0; n < 2; ++n)
                acc[m][n] = __builtin_amdgcn_mfma_f32_16x16x32_bf16(
                    af[m], bf[n], acc[m][n], 0, 0, 0);
    };

    for (int t = 0; t < NT; t += 2) {
        gstep(xa0, xa1, xb, t + 2);
        gstep(ya0, ya1, yb, t + 3);
    }

    // epilogue: C/D layout col=lane&15, row=(lane>>4)*4+reg
#pragma unroll
    for (int n = 0; n < 2; ++n) {
        int col = col0 + wn * 32 + n * 16 + lrow;
        float bb = bias[col];
#pragma unroll
        for (int m = 0; m < 4; ++m) {
            int rowb = row0 + wm * 64 + m * 16 + lk * 4;
#pragma unroll
            for (int r = 0; r < 4; ++r) {
                float v = acc[m][n][r] + bb;
                if (TANH) v = tanhf(v);
                if (OUTBF) ((short*)Cout)[(size_t)(rowb + r) * N + col] = f2bf(v);
                else       ((float*)Cout)[(size_t)(rowb + r) * N + col] = v;
            }
        }
    }
}

// ---------------------------------------------------------------------------
extern "C" void kernel_launch(void* const* d_in, const int* in_sizes, int n_in,
                              void* d_out, int out_size, void* d_ws, size_t ws_size,
                              hipStream_t stream) {
    const float* u     = (const float*)d_in[0];
    const float* D     = (const float*)d_in[1];
    const float* logdt = (const float*)d_in[2];
    const float* C_re  = (const float*)d_in[3];
    const float* C_im  = (const float*)d_in[4];
    const float* W1    = (const float*)d_in[5];
    const float* b1    = (const float*)d_in[6];
    const float* W2    = (const float*)d_in[7];
    const float* b2    = (const float*)d_in[8];
    float* out = (float*)d_out;

    char* p = (char*)d_ws;
    float4* tab = (float4*)p;            p += 262144;      // H*N2*16
    char* regionA = p;                   p += 33554432;    // POW+ktab, later Ybuf
    float2* POW  = (float2*)regionA;                       // 512*129*32*8
    float*  ktab = (float*)(regionA + 16908288);           // 512*128*4
    short*  Ybuf = (short*)regionA;                        // B*H*L*2 = 32 MB (b,h,l)
    short* Psw = (short*)p;              p += 25165824;    // 512*192*128*2
    short* Vsw = (short*)p;              p += 8388608;     // 512*128*64*2
    float* E   = (float*)p;              p += 33554432;    // 8192*16*64*4
    short* gbf = (short*)p;              p += 33554432;    // B*H*L*2
    short* tb  = (short*)p;              p += 16777216;    // 8192*1024*2
    short* w1t = (short*)p;              p += 4194304;
    short* w2t = (short*)p;

    k0_table<<<H_ * N2_ / 256, 256, 0, stream>>>(logdt, C_re, C_im, tab);
    t0_pow  <<<H_ * N2_ / 256, 256, 0, stream>>>(tab, POW);
    t_ktab  <<<H_ * 128 / 256, 256, 0, stream>>>(tab, POW, D, ktab);
    t1_fill <<<H_ * 320 * 8 / 256, 256, 0, stream>>>(tab, POW, ktab, Psw, Vsw);
    wtrans  <<<dim3(L_ / 32, 2 * H_ / 32), 256, 0, stream>>>(W1, w1t, L_, 2 * H_);
    wtrans  <<<dim3(2 * H_ / 32, H_ / 32), 256, 0, stream>>>(W2, w2t, 2 * H_, H_);

    conv_mfma  <<<H_, 512, 0, stream>>>(u, Psw, E, Ybuf);
    k2_scan    <<<B_ * H_ * N2_ / 256, 256, 0, stream>>>(logdt, (float2*)E);
    dcarry_mfma<<<dim3(H_, 2), 256, 0, stream>>>(E, Vsw, Ybuf, gbf);

    gemm_mfma<true, true ><<<dim3(B_ * H_ / 128, 2 * H_ / 64), 256, 0, stream>>>(
        gbf, w1t, b1, tb, B_ * H_, 2 * H_, L_);
    gemm_mfma<false, false><<<dim3(B_ * H_ / 128, H_ / 64), 256, 0, stream>>>(
        tb, w2t, b2, out, B_ * H_, H_, 2 * H_);
}

// Round 17
// 206.607 us; speedup vs baseline: 1.2406x; 1.0079x over previous
//
#include <hip/hip_runtime.h>
#include <math.h>

#define B_  16
#define H_  512
#define L_  2048
#define N2_ 32
#define NC_ 16
#define LC_ 128   // L_/NC_

typedef __attribute__((ext_vector_type(8))) short short8;
typedef __attribute__((ext_vector_type(4))) float f32x4;

__device__ __forceinline__ short f2bf(float x) {
    unsigned u = __builtin_bit_cast(unsigned, x);
    u += 0x7fffu + ((u >> 16) & 1u);           // round-to-nearest-even
    return (short)(u >> 16);
}
__device__ __forceinline__ float bf2f(unsigned short s) {
    unsigned u = ((unsigned)s) << 16;
    return __builtin_bit_cast(float, u);
}

// ---------------------------------------------------------------------------
// K0: per-(h,n) table: lambda = exp(dt*A), C' = (C_re+iC_im)*(lambda-1)/A
// ---------------------------------------------------------------------------
__global__ void k0_table(const float* __restrict__ log_dt,
                         const float* __restrict__ C_re,
                         const float* __restrict__ C_im,
                         float4* __restrict__ tab) {
    int idx = blockIdx.x * blockDim.x + threadIdx.x;   // h*N2 + n
    if (idx >= H_ * N2_) return;
    int h = idx >> 5, n = idx & 31;
    float dt = expf(log_dt[h]);
    float e  = expf(-0.5f * dt);
    float th = 3.14159265358979323846f * (float)n * dt;
    float lr = e * cosf(th), li = e * sinf(th);
    float ar = -0.5f, ai = 3.14159265358979323846f * (float)n;
    float den = ar * ar + ai * ai;
    float x = lr - 1.0f, y = li;
    float nr = (x * ar + y * ai) / den;
    float ni = (y * ar - x * ai) / den;
    float cr = C_re[idx], ci = C_im[idx];
    tab[idx] = make_float4(lr, li, cr * nr - ci * ni, cr * ni + ci * nr);
}

// ---------------------------------------------------------------------------
// T0: POW[h][m][n] = lambda_n^m, m = 0..128 (complex f32)
// ---------------------------------------------------------------------------
__global__ void t0_pow(const float4* __restrict__ tab, float2* __restrict__ POW) {
    int t = blockIdx.x * 256 + threadIdx.x;   // h*N2 + n
    if (t >= H_ * N2_) return;
    int h = t >> 5;
    float4 v = tab[t];
    float lr = v.x, li = v.y;
    float pr = 1.0f, pi = 0.0f;
    float2* base = POW + (size_t)h * 129 * N2_ + (t & 31);
    for (int m = 0; m <= 128; ++m) {
        base[(size_t)m * N2_] = make_float2(pr, pi);
        float npr = pr * lr - pi * li;
        float npi = pr * li + pi * lr;
        pr = npr; pi = npi;
    }
}

// ---------------------------------------------------------------------------
// ktab[h][m] = 2 * Re sum_n C'_n * lambda_n^m ; +D[h] at m=0 (folds D*u into
// the Toeplitz diagonal so the GELU stage never touches u).
// ---------------------------------------------------------------------------
__global__ void t_ktab(const float4* __restrict__ tab, const float2* __restrict__ POW,
                       const float* __restrict__ Dv, float* __restrict__ ktab) {
    int t = blockIdx.x * 256 + threadIdx.x;   // h*128 + m
    if (t >= H_ * 128) return;
    int h = t >> 7, m = t & 127;
    const float2* P = POW + (size_t)h * 129 * N2_ + (size_t)m * N2_;
    const float4* tb = tab + h * N2_;
    float s = 0.0f;
    for (int n = 0; n < N2_; ++n) {
        float2 p = P[n];
        float4 v = tb[n];
        s += v.z * p.x - v.w * p.y;
    }
    ktab[t] = 2.0f * s + (m == 0 ? Dv[h] : 0.0f);
}

// ---------------------------------------------------------------------------
// T1: fill Psw (pre-swizzled [h][g16][n192][8] bf16) and Vsw ([h][g8][l128][8]).
// ---------------------------------------------------------------------------
__global__ void __launch_bounds__(256)
t1_fill(const float4* __restrict__ tab, const float2* __restrict__ POW,
        const float* __restrict__ ktab, short* __restrict__ Psw,
        short* __restrict__ Vsw) {
    int t = blockIdx.x * 256 + threadIdx.x;
    int sub = t & 7;
    int rowg = t >> 3;
    int h = rowg / 320, row = rowg % 320;
    if (row < 192) {
        short8 s0, s1;
        if (row < 128) {
            int l = row;
#pragma unroll
            for (int mm = 0; mm < 8; ++mm) {
                int m0 = sub * 16 + mm, m1 = m0 + 8;
                s0[mm] = (m0 <= l) ? f2bf(ktab[h * 128 + (l - m0)]) : (short)0;
                s1[mm] = (m1 <= l) ? f2bf(ktab[h * 128 + (l - m1)]) : (short)0;
            }
        } else {
            int j = row - 128, nn = j >> 1, part = j & 1;
            const float2* P = POW + (size_t)h * 129 * N2_ + nn;
#pragma unroll
            for (int mm = 0; mm < 8; ++mm) {
                int m0 = sub * 16 + mm, m1 = m0 + 8;
                float2 p0 = P[(size_t)(127 - m0) * N2_];
                float2 p1 = P[(size_t)(127 - m1) * N2_];
                s0[mm] = f2bf(part ? p0.y : p0.x);
                s1[mm] = f2bf(part ? p1.y : p1.x);
            }
        }
        *(short8*)(Psw + ((size_t)(h * 16 + sub * 2 + 0) * 192 + row) * 8) = s0;
        *(short8*)(Psw + ((size_t)(h * 16 + sub * 2 + 1) * 192 + row) * 8) = s1;
    } else {
        int l = row - 192;
        const float2* P = POW + (size_t)h * 129 * N2_ + (size_t)(l + 1) * N2_;
        const float4* tb = tab + h * N2_;
        short8 s;
#pragma unroll
        for (int jj = 0; jj < 8; ++jj) {
            int j = sub * 8 + jj, nn = j >> 1;
            float2 p = P[nn];
            float4 cv = tb[nn];
            float re = cv.z * p.x - cv.w * p.y;
            float im = cv.z * p.y + cv.w * p.x;
            s[jj] = f2bf((j & 1) ? -2.0f * im : 2.0f * re);
        }
        *(short8*)(Vsw + ((size_t)(h * 8 + sub) * 128 + l) * 8) = s;
    }
}

// ---------------------------------------------------------------------------
// conv_mfma v3: ONE block per h (512 thr, 8 waves): Out(256x192) =
// U(256x128) @ P_h^T. Y epilogue staged through LDS then written coalesced.
// E (cols 128..191) written direct (64B segments).
// ---------------------------------------------------------------------------
__global__ void __launch_bounds__(512)
conv_mfma(const float* __restrict__ u, const short* __restrict__ Psw,
          float* __restrict__ E, short* __restrict__ Ybuf) {
    __shared__ char smem[65536];
    short* Ps = (short*)smem;                  // [16][192][8] 48K (conv)
    short* As = (short*)(smem + 49152);        // [4][256][8]  16K (conv)
    short* Ys = (short*)smem;                  // [256][128]   64K (post-conv)
    int h = blockIdx.x;
    int tid = threadIdx.x;
    {
        const short8* Pg = (const short8*)(Psw + (size_t)h * 24576);
        short8* PsV = (short8*)Ps;
#pragma unroll
        for (int j = 0; j < 6; ++j) PsV[tid + j * 512] = Pg[tid + j * 512];
    }
    int row = tid >> 1, half = tid & 1;      // row 0..255
    int b0 = row >> 4, c0 = row & 15;
    const float* up = u + ((size_t)(b0 * H_ + h)) * L_ + (size_t)c0 * LC_ + half * 16;
    short8* AsV = (short8*)As;

    int lane = tid & 63, wave = tid >> 6;    // 8 waves
    int wm = wave >> 1, wn = wave & 1;       // 4M x 2N
    int lrow = lane & 15, lk = lane >> 4;
    const short8* AsF = (const short8*)As;
    const short8* PsF = (const short8*)Ps;

    f32x4 acc[4][6] = {};
    float4 fv0 = *(const float4*)(up + 0);
    float4 fv1 = *(const float4*)(up + 4);
    float4 fv2 = *(const float4*)(up + 8);
    float4 fv3 = *(const float4*)(up + 12);
    for (int ks = 0; ks < 4; ++ks) {
        __syncthreads();
        short8 s0, s1;
        s0[0] = f2bf(fv0.x); s0[1] = f2bf(fv0.y); s0[2] = f2bf(fv0.z); s0[3] = f2bf(fv0.w);
        s0[4] = f2bf(fv1.x); s0[5] = f2bf(fv1.y); s0[6] = f2bf(fv1.z); s0[7] = f2bf(fv1.w);
        s1[0] = f2bf(fv2.x); s1[1] = f2bf(fv2.y); s1[2] = f2bf(fv2.z); s1[3] = f2bf(fv2.w);
        s1[4] = f2bf(fv3.x); s1[5] = f2bf(fv3.y); s1[6] = f2bf(fv3.z); s1[7] = f2bf(fv3.w);
        AsV[(half * 2 + 0) * 256 + row] = s0;
        AsV[(half * 2 + 1) * 256 + row] = s1;
        __syncthreads();
        if (ks < 3) {
            const float* nx = up + (ks + 1) * 32;
            fv0 = *(const float4*)(nx + 0);
            fv1 = *(const float4*)(nx + 4);
            fv2 = *(const float4*)(nx + 8);
            fv3 = *(const float4*)(nx + 12);
        }
        short8 af[4], bfr[6];
#pragma unroll
        for (int m = 0; m < 4; ++m)
            af[m] = AsF[lk * 256 + wm * 64 + m * 16 + lrow];
#pragma unroll
        for (int n = 0; n < 6; ++n)
            bfr[n] = PsF[(ks * 4 + lk) * 192 + wn * 96 + n * 16 + lrow];
#pragma unroll
        for (int m = 0; m < 4; ++m)
#pragma unroll
            for (int n = 0; n < 6; ++n)
                acc[m][n] = __builtin_amdgcn_mfma_f32_16x16x32_bf16(
                    af[m], bfr[n], acc[m][n], 0, 0, 0);
    }
    __syncthreads();   // conv LDS reads done; Ps/As reusable as Ys

    // Y fragments -> LDS stage; E fragments -> global direct
#pragma unroll
    for (int nf = 0; nf < 6; ++nf) {
        int col = wn * 96 + nf * 16 + lrow;
#pragma unroll
        for (int mf = 0; mf < 4; ++mf) {
            int rb = wm * 64 + mf * 16 + lk * 4;
#pragma unroll
            for (int r = 0; r < 4; ++r) {
                int Rr = rb + r;
                float vv = acc[mf][nf][r];
                if (col < 128) {
                    Ys[Rr * 128 + col] = f2bf(vv);
                } else {
                    int bb = Rr >> 4, cc = Rr & 15;
                    E[((size_t)(bb * H_ + h) * NC_ + cc) * 64 + (col - 128)] = vv;
                }
            }
        }
    }
    __syncthreads();

    // coalesced copy-out: 16-lane group writes one full 256B Ybuf row
    const short8* YsV = (const short8*)Ys;
#pragma unroll
    for (int it = 0; it < 8; ++it) {
        int sidx = it * 512 + tid;          // short8 index, 0..4095
        int rr = sidx >> 4;                 // local row 0..255
        int colq = sidx & 15;               // short8 within row
        int bb = rr >> 4, cc = rr & 15;
        *(short8*)(Ybuf + ((size_t)(bb * H_ + h)) * L_ + (size_t)cc * LC_ + colq * 8)
            = YsV[sidx];
    }
}

// ---------------------------------------------------------------------------
// K2: per-(b,h,n) serial scan over chunks (exclusive -> S at chunk start).
// ---------------------------------------------------------------------------
__global__ void k2_scan(const float* __restrict__ log_dt, float2* __restrict__ ES) {
    int t = blockIdx.x * 256 + threadIdx.x;
    if (t >= B_ * H_ * N2_) return;
    int n  = t & 31;
    int h  = (t >> 5) & (H_ - 1);
    int bh = t >> 5;
    float dt = expf(log_dt[h]);
    float e  = expf(-0.5f * dt * (float)LC_);
    float th = 3.14159265358979323846f * (float)n * dt * (float)LC_;
    float Lr = e * cosf(th), Li = e * sinf(th);
    float cr = 0.0f, ci = 0.0f;
    float2* base = ES + (size_t)bh * NC_ * N2_ + n;
#pragma unroll
    for (int c = 0; c < NC_; ++c) {
        float2 Ev = base[(size_t)c * N2_];
        base[(size_t)c * N2_] = make_float2(cr, ci);
        float ncr = fmaf(Lr, cr, fmaf(-Li, ci, Ev.x));
        float nci = fmaf(Lr, ci, fmaf(Li, cr, Ev.y));
        cr = ncr; ci = nci;
    }
}

// ---------------------------------------------------------------------------
// dcarry_mfma v2: per (h, mh): Carry(128x128) = S(128x64) @ V_h^T via MFMA.
// Carry fragments staged in LDS (aliasing dead Sa/Vb), then fused coalesced
// epilogue: gbf = bf16(GELU(Ybuf + carry)) in full short8 rows.
// ---------------------------------------------------------------------------
__global__ void __launch_bounds__(256)
dcarry_mfma(const float* __restrict__ ES, const short* __restrict__ Vsw,
            const short* __restrict__ Ybuf, short* __restrict__ gbf) {
    __shared__ char smem[32768];
    short* Sa = (short*)smem;             // [8][128][8] 16 KB
    short* Vb = (short*)(smem + 16384);   // [8][128][8] 16 KB
    short* Ys = (short*)smem;             // [128][128]  32 KB (post-MFMA)
    int h = blockIdx.x, mh = blockIdx.y;
    int tid = threadIdx.x;
    {
        const short8* Vg = (const short8*)(Vsw + (size_t)h * 8192);
        short8* VbV = (short8*)Vb;
#pragma unroll
        for (int j = 0; j < 4; ++j) VbV[tid + j * 256] = Vg[tid + j * 256];
    }
    int row = tid >> 1, half = tid & 1;
    int R = mh * 128 + row, b = R >> 4, c = R & 15;
    {
        const float* sp = ES + ((size_t)(b * H_ + h) * NC_ + c) * 64 + half * 32;
        short8* SaV = (short8*)Sa;
#pragma unroll
        for (int gg = 0; gg < 4; ++gg) {
            float4 f0 = *(const float4*)(sp + gg * 8);
            float4 f1 = *(const float4*)(sp + gg * 8 + 4);
            short8 s;
            s[0] = f2bf(f0.x); s[1] = f2bf(f0.y); s[2] = f2bf(f0.z); s[3] = f2bf(f0.w);
            s[4] = f2bf(f1.x); s[5] = f2bf(f1.y); s[6] = f2bf(f1.z); s[7] = f2bf(f1.w);
            SaV[(half * 4 + gg) * 128 + row] = s;
        }
    }
    __syncthreads();
    int lane = tid & 63, wave = tid >> 6;
    int wm = wave >> 1, wn = wave & 1;
    int lrow = lane & 15, lk = lane >> 4;
    const short8* SaF = (const short8*)Sa;
    const short8* VbF = (const short8*)Vb;
    f32x4 acc[4][4] = {};
#pragma unroll
    for (int ks = 0; ks < 2; ++ks) {
        int g = ks * 4 + lk;
        short8 af[4], bf[4];
#pragma unroll
        for (int m = 0; m < 4; ++m)
            af[m] = SaF[g * 128 + wm * 64 + m * 16 + lrow];
#pragma unroll
        for (int n = 0; n < 4; ++n)
            bf[n] = VbF[g * 128 + wn * 64 + n * 16 + lrow];
#pragma unroll
        for (int m = 0; m < 4; ++m)
#pragma unroll
            for (int n = 0; n < 4; ++n)
                acc[m][n] = __builtin_amdgcn_mfma_f32_16x16x32_bf16(
                    af[m], bf[n], acc[m][n], 0, 0, 0);
    }
    __syncthreads();   // Sa/Vb reads done -> reuse as Ys

    // carry fragments -> LDS stage (bf16, same precision as before)
#pragma unroll
    for (int nf = 0; nf < 4; ++nf) {
        int l = wn * 64 + nf * 16 + lrow;
#pragma unroll
        for (int mf = 0; mf < 4; ++mf) {
            int rb = wm * 64 + mf * 16 + lk * 4;
#pragma unroll
            for (int r = 0; r < 4; ++r)
                Ys[(rb + r) * 128 + l] = f2bf(acc[mf][nf][r]);
        }
    }
    __syncthreads();

    // fused coalesced epilogue: gbf = bf16(GELU(Ybuf + carry)), short8 rows
    const short8* YsV = (const short8*)Ys;
#pragma unroll
    for (int it = 0; it < 8; ++it) {
        int sidx = it * 256 + tid;          // 0..2047
        int rr = sidx >> 4;                 // local row 0..127
        int colq = sidx & 15;
        int Rr = mh * 128 + rr, bb = Rr >> 4, cc = Rr & 15;
        size_t gaddr = ((size_t)(bb * H_ + h)) * L_ + (size_t)cc * LC_ + colq * 8;
        short8 yv = *(const short8*)(Ybuf + gaddr);
        short8 cv = YsV[sidx];
        short8 o;
#pragma unroll
        for (int j = 0; j < 8; ++j) {
            float y = bf2f((unsigned short)yv[j]) + bf2f((unsigned short)cv[j]);
            o[j] = f2bf(0.5f * y * (1.0f + erff(y * 0.70710678118654752f)));
        }
        *(short8*)(gbf + gaddr) = o;
    }
}

// ---------------------------------------------------------------------------
// W transpose + f32->bf16: Wt[n][k] = bf16(W[k][n])
// ---------------------------------------------------------------------------
__global__ void __launch_bounds__(256)
wtrans(const float* __restrict__ W, short* __restrict__ Wt, int K, int N) {
    __shared__ short tile[32][33];
    int bk = blockIdx.x * 32, bn = blockIdx.y * 32;
    int tx = threadIdx.x & 31, ty = threadIdx.x >> 5;   // ty 0..7
#pragma unroll
    for (int i = 0; i < 4; ++i)
        tile[ty + i * 8][tx] = f2bf(W[(size_t)(bk + ty + i * 8) * N + bn + tx]);
    __syncthreads();
#pragma unroll
    for (int i = 0; i < 4; ++i)
        Wt[(size_t)(bn + ty + i * 8) * K + bk + tx] = tile[tx][ty + i * 8];
}

// ---------------------------------------------------------------------------
// bf16 MFMA GEMM v8 "wide" (GEMM1): 256x128 tile, 8 waves (512 thr),
// wave grid 4M x 2N, wave tile 64x64 (acc 4x4): ds_reads per MFMA drop
// 0.75 -> 0.5 and per-CU LDS traffic per K-step 128KB -> 88KB vs v5,
// at same MFMA/CU-step (128). Occupancy 1 block/CU (2 waves/SIMD) —
// testing reads/MFMA vs wave-count tradeoff (r10 confounded both).
// [36]-strided LDS, 2-deep named prefetch, 64B-coalesced staging,
// grid dim3(M/256, N/128): XCD = row-panel%8.
// ---------------------------------------------------------------------------
template<bool TANH, bool OUTBF>
__global__ void __launch_bounds__(512)
gemm_mfma_w(const short* __restrict__ A, const short* __restrict__ Bt,
            const float* __restrict__ bias, void* __restrict__ Cout,
            int M, int N, int K) {
    __shared__ short As[256 * 36 + 8];
    __shared__ short Bs[128 * 36 + 8];
    int tid  = threadIdx.x;
    int lane = tid & 63;
    int wave = tid >> 6;                 // 0..7
    int wm = wave >> 1, wn = wave & 1;   // 4M x 2N, wave tile 64x64
    int lrow = lane & 15, lk = lane >> 4;
    int row0 = blockIdx.x * 256, col0 = blockIdx.y * 128;

    // A staging: 2 thr/row, 16 shorts each (32B); B: 4 thr/row, 8 shorts
    int arow = tid >> 1, ak = (tid & 1) * 16;
    const short* AgP = A + (size_t)(row0 + arow) * K + ak;
    int saA = arow * 36 + ak;
    int brow = tid >> 2, bk = (tid & 3) * 8;
    const short* BgP = Bt + (size_t)(col0 + brow) * K + bk;
    int saB = brow * 36 + bk;

    f32x4 acc[4][4] = {};
    const int NT = K >> 5;          // 64 (GEMM1) — even

    // two statically-named prefetch sets (rule #20)
    short8 xa0 = *(const short8*)(AgP),      xa1 = *(const short8*)(AgP + 8);
    short8 xb  = *(const short8*)(BgP);
    short8 ya0 = *(const short8*)(AgP + 32), ya1 = *(const short8*)(AgP + 40);
    short8 yb  = *(const short8*)(BgP + 32);

    auto gstep = [&](short8& A0, short8& A1, short8& Bv, int tnext) {
        __syncthreads();
        *(short8*)&As[saA]     = A0;
        *(short8*)&As[saA + 8] = A1;
        *(short8*)&Bs[saB]     = Bv;
        __syncthreads();
        if (tnext < NT) {
            int ko = tnext << 5;
            A0 = *(const short8*)(AgP + ko);
            A1 = *(const short8*)(AgP + ko + 8);
            Bv = *(const short8*)(BgP + ko);
        }
        short8 af[4], bf[4];
#pragma unroll
        for (int m = 0; m < 4; ++m)
            af[m] = *(const short8*)&As[(wm * 64 + m * 16 + lrow) * 36 + lk * 8];
#pragma unroll
        for (int n = 0; n < 4; ++n)
            bf[n] = *(const short8*)&Bs[(wn * 64 + n * 16 + lrow) * 36 + lk * 8];
#pragma unroll
        for (int m = 0; m < 4; ++m)
#pragma unroll
            for (int n = 0; n < 4; ++n)
                acc[m][n] = __builtin_amdgcn_mfma_f32_16x16x32_bf16(
                    af[m], bf[n], acc[m][n], 0, 0, 0);
    };

    for (int t = 0; t < NT; t += 2) {
        gstep(xa0, xa1, xb, t + 2);
        gstep(ya0, ya1, yb, t + 3);
    }

    // epilogue: C/D layout col=lane&15, row=(lane>>4)*4+reg
#pragma unroll
    for (int n = 0; n < 4; ++n) {
        int col = col0 + wn * 64 + n * 16 + lrow;
        float bb = bias[col];
#pragma unroll
        for (int m = 0; m < 4; ++m) {
            int rowb = row0 + wm * 64 + m * 16 + lk * 4;
#pragma unroll
            for (int r = 0; r < 4; ++r) {
                float v = acc[m][n][r] + bb;
                if (TANH) v = tanhf(v);
                if (OUTBF) ((short*)Cout)[(size_t)(rowb + r) * N + col] = f2bf(v);
                else       ((float*)Cout)[(size_t)(rowb + r) * N + col] = v;
            }
        }
    }
}

// ---------------------------------------------------------------------------
// bf16 MFMA GEMM v5 (GEMM2): 8 waves / 512 thr / 128x128 tile,
// double-buffered LDS, one barrier per K-step. Wave 64x32, acc 4x2.
// ---------------------------------------------------------------------------
template<bool TANH, bool OUTBF>
__global__ void __launch_bounds__(512)
gemm_mfma(const short* __restrict__ A, const short* __restrict__ Bt,
          const float* __restrict__ bias, void* __restrict__ Cout,
          int M, int N, int K) {
    __shared__ short As[2][128 * 36];
    __shared__ short Bs[2][128 * 36];
    int tid  = threadIdx.x;
    int lane = tid & 63;
    int wave = tid >> 6;                 // 0..7
    int wm = wave >> 2, wn = wave & 3;   // 2M x 4N
    int lrow = lane & 15, kblk = lane >> 4;
    int row0 = blockIdx.x * 128, col0 = blockIdx.y * 128;

    int srow = tid >> 2;            // 0..127
    int sk   = (tid & 3) * 8;       // k offset (shorts)
    const short* Ag = A  + (size_t)(row0 + srow) * K + sk;
    const short* Bg = Bt + (size_t)(col0 + srow) * K + sk;
    int si = srow * 36 + sk;

    f32x4 acc[4][2] = {};
    const int NT = K >> 5;          // even

    short8 pa = *(const short8*)(Ag),      pb = *(const short8*)(Bg);
    *(short8*)&As[0][si] = pa;
    *(short8*)&Bs[0][si] = pb;
    short8 qa = *(const short8*)(Ag + 32), qb = *(const short8*)(Bg + 32);
    __syncthreads();

    for (int t = 0; t < NT; t += 2) {
        if (t + 2 < NT) {
            int ko = (t + 2) << 5;
            pa = *(const short8*)(Ag + ko);
            pb = *(const short8*)(Bg + ko);
        }
        {
            short8 af[4], bf[2];
#pragma unroll
            for (int m = 0; m < 4; ++m)
                af[m] = *(const short8*)&As[0][(wm * 64 + m * 16 + lrow) * 36 + kblk * 8];
#pragma unroll
            for (int n = 0; n < 2; ++n)
                bf[n] = *(const short8*)&Bs[0][(wn * 32 + n * 16 + lrow) * 36 + kblk * 8];
#pragma unroll
            for (int m = 0; m < 4; ++m)
#pragma unroll
                for (int n = 0; n < 2; ++n)
                    acc[m][n] = __builtin_amdgcn_mfma_f32_16x16x32_bf16(
                        af[m], bf[n], acc[m][n], 0, 0, 0);
        }
        *(short8*)&As[1][si] = qa;
        *(short8*)&Bs[1][si] = qb;
        __syncthreads();

        if (t + 3 < NT) {
            int ko = (t + 3) << 5;
            qa = *(const short8*)(Ag + ko);
            qb = *(const short8*)(Bg + ko);
        }
        {
            short8 af[4], bf[2];
#pragma unroll
            for (int m = 0; m < 4; ++m)
                af[m] = *(const short8*)&As[1][(wm * 64 + m * 16 + lrow) * 36 + kblk * 8];
#pragma unroll
            for (int n = 0; n < 2; ++n)
                bf[n] = *(const short8*)&Bs[1][(wn * 32 + n * 16 + lrow) * 36 + kblk * 8];
#pragma unroll
            for (int m = 0; m < 4; ++m)
#pragma unroll
                for (int n = 0; n < 2; ++n)
                    acc[m][n] = __builtin_amdgcn_mfma_f32_16x16x32_bf16(
                        af[m], bf[n], acc[m][n], 0, 0, 0);
        }
        if (t + 2 < NT) {
            *(short8*)&As[0][si] = pa;
            *(short8*)&Bs[0][si] = pb;
        }
        __syncthreads();
    }

#pragma unroll
    for (int n = 0; n < 2; ++n) {
        int col = col0 + wn * 32 + n * 16 + lrow;
        float bb = bias[col];
#pragma unroll
        for (int m = 0; m < 4; ++m) {
            int rowb = row0 + wm * 64 + m * 16 + kblk * 4;
#pragma unroll
            for (int r = 0; r < 4; ++r) {
                float v = acc[m][n][r] + bb;
                if (TANH) v = tanhf(v);
                if (OUTBF) ((short*)Cout)[(size_t)(rowb + r) * N + col] = f2bf(v);
                else       ((float*)Cout)[(size_t)(rowb + r) * N + col] = v;
            }
        }
    }
}

// ---------------------------------------------------------------------------
extern "C" void kernel_launch(void* const* d_in, const int* in_sizes, int n_in,
                              void* d_out, int out_size, void* d_ws, size_t ws_size,
                              hipStream_t stream) {
    const float* u     = (const float*)d_in[0];
    const float* D     = (const float*)d_in[1];
    const float* logdt = (const float*)d_in[2];
    const float* C_re  = (const float*)d_in[3];
    const float* C_im  = (const float*)d_in[4];
    const float* W1    = (const float*)d_in[5];
    const float* b1    = (const float*)d_in[6];
    const float* W2    = (const float*)d_in[7];
    const float* b2    = (const float*)d_in[8];
    float* out = (float*)d_out;

    char* p = (char*)d_ws;
    float4* tab = (float4*)p;            p += 262144;      // H*N2*16
    char* regionA = p;                   p += 33554432;    // POW+ktab, later Ybuf
    float2* POW  = (float2*)regionA;                       // 512*129*32*8
    float*  ktab = (float*)(regionA + 16908288);           // 512*128*4
    short*  Ybuf = (short*)regionA;                        // B*H*L*2 = 32 MB (b,h,l)
    short* Psw = (short*)p;              p += 25165824;    // 512*192*128*2
    short* Vsw = (short*)p;              p += 8388608;     // 512*128*64*2
    float* E   = (float*)p;              p += 33554432;    // 8192*16*64*4
    short* gbf = (short*)p;              p += 33554432;    // B*H*L*2
    short* tb  = (short*)p;              p += 16777216;    // 8192*1024*2
    short* w1t = (short*)p;              p += 4194304;
    short* w2t = (short*)p;

    k0_table<<<H_ * N2_ / 256, 256, 0, stream>>>(logdt, C_re, C_im, tab);
    t0_pow  <<<H_ * N2_ / 256, 256, 0, stream>>>(tab, POW);
    t_ktab  <<<H_ * 128 / 256, 256, 0, stream>>>(tab, POW, D, ktab);
    t1_fill <<<H_ * 320 * 8 / 256, 256, 0, stream>>>(tab, POW, ktab, Psw, Vsw);
    wtrans  <<<dim3(L_ / 32, 2 * H_ / 32), 256, 0, stream>>>(W1, w1t, L_, 2 * H_);
    wtrans  <<<dim3(2 * H_ / 32, H_ / 32), 256, 0, stream>>>(W2, w2t, 2 * H_, H_);

    conv_mfma  <<<H_, 512, 0, stream>>>(u, Psw, E, Ybuf);
    k2_scan    <<<B_ * H_ * N2_ / 256, 256, 0, stream>>>(logdt, (float2*)E);
    dcarry_mfma<<<dim3(H_, 2), 256, 0, stream>>>(E, Vsw, Ybuf, gbf);

    gemm_mfma_w<true, true ><<<dim3(B_ * H_ / 256, 2 * H_ / 128), 512, 0, stream>>>(
        gbf, w1t, b1, tb, B_ * H_, 2 * H_, L_);
    gemm_mfma<false, false><<<dim3(B_ * H_ / 128, H_ / 128), 512, 0, stream>>>(
        tb, w2t, b2, out, B_ * H_, H_, 2 * H_);
}

// Round 18
// 192.336 us; speedup vs baseline: 1.3326x; 1.0742x over previous
//
#include <hip/hip_runtime.h>
#include <math.h>

#define B_  16
#define H_  512
#define L_  2048
#define N2_ 32
#define NC_ 16
#define LC_ 128   // L_/NC_

typedef __attribute__((ext_vector_type(8))) short short8;
typedef __attribute__((ext_vector_type(4))) float f32x4;

__device__ __forceinline__ short f2bf(float x) {
    unsigned u = __builtin_bit_cast(unsigned, x);
    u += 0x7fffu + ((u >> 16) & 1u);           // round-to-nearest-even
    return (short)(u >> 16);
}
__device__ __forceinline__ float bf2f(unsigned short s) {
    unsigned u = ((unsigned)s) << 16;
    return __builtin_bit_cast(float, u);
}

// ---------------------------------------------------------------------------
// K0: per-(h,n) table: lambda = exp(dt*A), C' = (C_re+iC_im)*(lambda-1)/A
// ---------------------------------------------------------------------------
__global__ void k0_table(const float* __restrict__ log_dt,
                         const float* __restrict__ C_re,
                         const float* __restrict__ C_im,
                         float4* __restrict__ tab) {
    int idx = blockIdx.x * blockDim.x + threadIdx.x;   // h*N2 + n
    if (idx >= H_ * N2_) return;
    int h = idx >> 5, n = idx & 31;
    float dt = expf(log_dt[h]);
    float e  = expf(-0.5f * dt);
    float th = 3.14159265358979323846f * (float)n * dt;
    float lr = e * cosf(th), li = e * sinf(th);
    float ar = -0.5f, ai = 3.14159265358979323846f * (float)n;
    float den = ar * ar + ai * ai;
    float x = lr - 1.0f, y = li;
    float nr = (x * ar + y * ai) / den;
    float ni = (y * ar - x * ai) / den;
    float cr = C_re[idx], ci = C_im[idx];
    tab[idx] = make_float4(lr, li, cr * nr - ci * ni, cr * ni + ci * nr);
}

// ---------------------------------------------------------------------------
// T0: POW[h][m][n] = lambda_n^m, m = 0..128 (complex f32)
// ---------------------------------------------------------------------------
__global__ void t0_pow(const float4* __restrict__ tab, float2* __restrict__ POW) {
    int t = blockIdx.x * 256 + threadIdx.x;   // h*N2 + n
    if (t >= H_ * N2_) return;
    int h = t >> 5;
    float4 v = tab[t];
    float lr = v.x, li = v.y;
    float pr = 1.0f, pi = 0.0f;
    float2* base = POW + (size_t)h * 129 * N2_ + (t & 31);
    for (int m = 0; m <= 128; ++m) {
        base[(size_t)m * N2_] = make_float2(pr, pi);
        float npr = pr * lr - pi * li;
        float npi = pr * li + pi * lr;
        pr = npr; pi = npi;
    }
}

// ---------------------------------------------------------------------------
// ktab[h][m] = 2 * Re sum_n C'_n * lambda_n^m ; +D[h] at m=0 (folds D*u into
// the Toeplitz diagonal so the GELU stage never touches u).
// ---------------------------------------------------------------------------
__global__ void t_ktab(const float4* __restrict__ tab, const float2* __restrict__ POW,
                       const float* __restrict__ Dv, float* __restrict__ ktab) {
    int t = blockIdx.x * 256 + threadIdx.x;   // h*128 + m
    if (t >= H_ * 128) return;
    int h = t >> 7, m = t & 127;
    const float2* P = POW + (size_t)h * 129 * N2_ + (size_t)m * N2_;
    const float4* tb = tab + h * N2_;
    float s = 0.0f;
    for (int n = 0; n < N2_; ++n) {
        float2 p = P[n];
        float4 v = tb[n];
        s += v.z * p.x - v.w * p.y;
    }
    ktab[t] = 2.0f * s + (m == 0 ? Dv[h] : 0.0f);
}

// ---------------------------------------------------------------------------
// T1: fill Psw (pre-swizzled [h][g16][n192][8] bf16) and Vsw ([h][g8][l128][8]).
// ---------------------------------------------------------------------------
__global__ void __launch_bounds__(256)
t1_fill(const float4* __restrict__ tab, const float2* __restrict__ POW,
        const float* __restrict__ ktab, short* __restrict__ Psw,
        short* __restrict__ Vsw) {
    int t = blockIdx.x * 256 + threadIdx.x;
    int sub = t & 7;
    int rowg = t >> 3;
    int h = rowg / 320, row = rowg % 320;
    if (row < 192) {
        short8 s0, s1;
        if (row < 128) {
            int l = row;
#pragma unroll
            for (int mm = 0; mm < 8; ++mm) {
                int m0 = sub * 16 + mm, m1 = m0 + 8;
                s0[mm] = (m0 <= l) ? f2bf(ktab[h * 128 + (l - m0)]) : (short)0;
                s1[mm] = (m1 <= l) ? f2bf(ktab[h * 128 + (l - m1)]) : (short)0;
            }
        } else {
            int j = row - 128, nn = j >> 1, part = j & 1;
            const float2* P = POW + (size_t)h * 129 * N2_ + nn;
#pragma unroll
            for (int mm = 0; mm < 8; ++mm) {
                int m0 = sub * 16 + mm, m1 = m0 + 8;
                float2 p0 = P[(size_t)(127 - m0) * N2_];
                float2 p1 = P[(size_t)(127 - m1) * N2_];
                s0[mm] = f2bf(part ? p0.y : p0.x);
                s1[mm] = f2bf(part ? p1.y : p1.x);
            }
        }
        *(short8*)(Psw + ((size_t)(h * 16 + sub * 2 + 0) * 192 + row) * 8) = s0;
        *(short8*)(Psw + ((size_t)(h * 16 + sub * 2 + 1) * 192 + row) * 8) = s1;
    } else {
        int l = row - 192;
        const float2* P = POW + (size_t)h * 129 * N2_ + (size_t)(l + 1) * N2_;
        const float4* tb = tab + h * N2_;
        short8 s;
#pragma unroll
        for (int jj = 0; jj < 8; ++jj) {
            int j = sub * 8 + jj, nn = j >> 1;
            float2 p = P[nn];
            float4 cv = tb[nn];
            float re = cv.z * p.x - cv.w * p.y;
            float im = cv.z * p.y + cv.w * p.x;
            s[jj] = f2bf((j & 1) ? -2.0f * im : 2.0f * re);
        }
        *(short8*)(Vsw + ((size_t)(h * 8 + sub) * 128 + l) * 8) = s;
    }
}

// ---------------------------------------------------------------------------
// conv_mfma v3: ONE block per h (512 thr, 8 waves): Out(256x192) =
// U(256x128) @ P_h^T. Y epilogue staged through LDS then written coalesced.
// E (cols 128..191) written direct (64B segments).
// ---------------------------------------------------------------------------
__global__ void __launch_bounds__(512)
conv_mfma(const float* __restrict__ u, const short* __restrict__ Psw,
          float* __restrict__ E, short* __restrict__ Ybuf) {
    __shared__ char smem[65536];
    short* Ps = (short*)smem;                  // [16][192][8] 48K (conv)
    short* As = (short*)(smem + 49152);        // [4][256][8]  16K (conv)
    short* Ys = (short*)smem;                  // [256][128]   64K (post-conv)
    int h = blockIdx.x;
    int tid = threadIdx.x;
    {
        const short8* Pg = (const short8*)(Psw + (size_t)h * 24576);
        short8* PsV = (short8*)Ps;
#pragma unroll
        for (int j = 0; j < 6; ++j) PsV[tid + j * 512] = Pg[tid + j * 512];
    }
    int row = tid >> 1, half = tid & 1;      // row 0..255
    int b0 = row >> 4, c0 = row & 15;
    const float* up = u + ((size_t)(b0 * H_ + h)) * L_ + (size_t)c0 * LC_ + half * 16;
    short8* AsV = (short8*)As;

    int lane = tid & 63, wave = tid >> 6;    // 8 waves
    int wm = wave >> 1, wn = wave & 1;       // 4M x 2N
    int lrow = lane & 15, lk = lane >> 4;
    const short8* AsF = (const short8*)As;
    const short8* PsF = (const short8*)Ps;

    f32x4 acc[4][6] = {};
    float4 fv0 = *(const float4*)(up + 0);
    float4 fv1 = *(const float4*)(up + 4);
    float4 fv2 = *(const float4*)(up + 8);
    float4 fv3 = *(const float4*)(up + 12);
    for (int ks = 0; ks < 4; ++ks) {
        __syncthreads();
        short8 s0, s1;
        s0[0] = f2bf(fv0.x); s0[1] = f2bf(fv0.y); s0[2] = f2bf(fv0.z); s0[3] = f2bf(fv0.w);
        s0[4] = f2bf(fv1.x); s0[5] = f2bf(fv1.y); s0[6] = f2bf(fv1.z); s0[7] = f2bf(fv1.w);
        s1[0] = f2bf(fv2.x); s1[1] = f2bf(fv2.y); s1[2] = f2bf(fv2.z); s1[3] = f2bf(fv2.w);
        s1[4] = f2bf(fv3.x); s1[5] = f2bf(fv3.y); s1[6] = f2bf(fv3.z); s1[7] = f2bf(fv3.w);
        AsV[(half * 2 + 0) * 256 + row] = s0;
        AsV[(half * 2 + 1) * 256 + row] = s1;
        __syncthreads();
        if (ks < 3) {
            const float* nx = up + (ks + 1) * 32;
            fv0 = *(const float4*)(nx + 0);
            fv1 = *(const float4*)(nx + 4);
            fv2 = *(const float4*)(nx + 8);
            fv3 = *(const float4*)(nx + 12);
        }
        short8 af[4], bfr[6];
#pragma unroll
        for (int m = 0; m < 4; ++m)
            af[m] = AsF[lk * 256 + wm * 64 + m * 16 + lrow];
#pragma unroll
        for (int n = 0; n < 6; ++n)
            bfr[n] = PsF[(ks * 4 + lk) * 192 + wn * 96 + n * 16 + lrow];
#pragma unroll
        for (int m = 0; m < 4; ++m)
#pragma unroll
            for (int n = 0; n < 6; ++n)
                acc[m][n] = __builtin_amdgcn_mfma_f32_16x16x32_bf16(
                    af[m], bfr[n], acc[m][n], 0, 0, 0);
    }
    __syncthreads();   // conv LDS reads done; Ps/As reusable as Ys

    // Y fragments -> LDS stage; E fragments -> global direct
#pragma unroll
    for (int nf = 0; nf < 6; ++nf) {
        int col = wn * 96 + nf * 16 + lrow;
#pragma unroll
        for (int mf = 0; mf < 4; ++mf) {
            int rb = wm * 64 + mf * 16 + lk * 4;
#pragma unroll
            for (int r = 0; r < 4; ++r) {
                int Rr = rb + r;
                float vv = acc[mf][nf][r];
                if (col < 128) {
                    Ys[Rr * 128 + col] = f2bf(vv);
                } else {
                    int bb = Rr >> 4, cc = Rr & 15;
                    E[((size_t)(bb * H_ + h) * NC_ + cc) * 64 + (col - 128)] = vv;
                }
            }
        }
    }
    __syncthreads();

    // coalesced copy-out: 16-lane group writes one full 256B Ybuf row
    const short8* YsV = (const short8*)Ys;
#pragma unroll
    for (int it = 0; it < 8; ++it) {
        int sidx = it * 512 + tid;          // short8 index, 0..4095
        int rr = sidx >> 4;                 // local row 0..255
        int colq = sidx & 15;               // short8 within row
        int bb = rr >> 4, cc = rr & 15;
        *(short8*)(Ybuf + ((size_t)(bb * H_ + h)) * L_ + (size_t)cc * LC_ + colq * 8)
            = YsV[sidx];
    }
}

// ---------------------------------------------------------------------------
// K2: per-(b,h,n) serial scan over chunks (exclusive -> S at chunk start).
// ---------------------------------------------------------------------------
__global__ void k2_scan(const float* __restrict__ log_dt, float2* __restrict__ ES) {
    int t = blockIdx.x * 256 + threadIdx.x;
    if (t >= B_ * H_ * N2_) return;
    int n  = t & 31;
    int h  = (t >> 5) & (H_ - 1);
    int bh = t >> 5;
    float dt = expf(log_dt[h]);
    float e  = expf(-0.5f * dt * (float)LC_);
    float th = 3.14159265358979323846f * (float)n * dt * (float)LC_;
    float Lr = e * cosf(th), Li = e * sinf(th);
    float cr = 0.0f, ci = 0.0f;
    float2* base = ES + (size_t)bh * NC_ * N2_ + n;
#pragma unroll
    for (int c = 0; c < NC_; ++c) {
        float2 Ev = base[(size_t)c * N2_];
        base[(size_t)c * N2_] = make_float2(cr, ci);
        float ncr = fmaf(Lr, cr, fmaf(-Li, ci, Ev.x));
        float nci = fmaf(Lr, ci, fmaf(Li, cr, Ev.y));
        cr = ncr; ci = nci;
    }
}

// ---------------------------------------------------------------------------
// dcarry_mfma v2: per (h, mh): Carry(128x128) = S(128x64) @ V_h^T via MFMA.
// Carry fragments staged in LDS (aliasing dead Sa/Vb), then fused coalesced
// epilogue: gbf = bf16(GELU(Ybuf + carry)) in full short8 rows.
// ---------------------------------------------------------------------------
__global__ void __launch_bounds__(256)
dcarry_mfma(const float* __restrict__ ES, const short* __restrict__ Vsw,
            const short* __restrict__ Ybuf, short* __restrict__ gbf) {
    __shared__ char smem[32768];
    short* Sa = (short*)smem;             // [8][128][8] 16 KB
    short* Vb = (short*)(smem + 16384);   // [8][128][8] 16 KB
    short* Ys = (short*)smem;             // [128][128]  32 KB (post-MFMA)
    int h = blockIdx.x, mh = blockIdx.y;
    int tid = threadIdx.x;
    {
        const short8* Vg = (const short8*)(Vsw + (size_t)h * 8192);
        short8* VbV = (short8*)Vb;
#pragma unroll
        for (int j = 0; j < 4; ++j) VbV[tid + j * 256] = Vg[tid + j * 256];
    }
    int row = tid >> 1, half = tid & 1;
    int R = mh * 128 + row, b = R >> 4, c = R & 15;
    {
        const float* sp = ES + ((size_t)(b * H_ + h) * NC_ + c) * 64 + half * 32;
        short8* SaV = (short8*)Sa;
#pragma unroll
        for (int gg = 0; gg < 4; ++gg) {
            float4 f0 = *(const float4*)(sp + gg * 8);
            float4 f1 = *(const float4*)(sp + gg * 8 + 4);
            short8 s;
            s[0] = f2bf(f0.x); s[1] = f2bf(f0.y); s[2] = f2bf(f0.z); s[3] = f2bf(f0.w);
            s[4] = f2bf(f1.x); s[5] = f2bf(f1.y); s[6] = f2bf(f1.z); s[7] = f2bf(f1.w);
            SaV[(half * 4 + gg) * 128 + row] = s;
        }
    }
    __syncthreads();
    int lane = tid & 63, wave = tid >> 6;
    int wm = wave >> 1, wn = wave & 1;
    int lrow = lane & 15, lk = lane >> 4;
    const short8* SaF = (const short8*)Sa;
    const short8* VbF = (const short8*)Vb;
    f32x4 acc[4][4] = {};
#pragma unroll
    for (int ks = 0; ks < 2; ++ks) {
        int g = ks * 4 + lk;
        short8 af[4], bf[4];
#pragma unroll
        for (int m = 0; m < 4; ++m)
            af[m] = SaF[g * 128 + wm * 64 + m * 16 + lrow];
#pragma unroll
        for (int n = 0; n < 4; ++n)
            bf[n] = VbF[g * 128 + wn * 64 + n * 16 + lrow];
#pragma unroll
        for (int m = 0; m < 4; ++m)
#pragma unroll
            for (int n = 0; n < 4; ++n)
                acc[m][n] = __builtin_amdgcn_mfma_f32_16x16x32_bf16(
                    af[m], bf[n], acc[m][n], 0, 0, 0);
    }
    __syncthreads();   // Sa/Vb reads done -> reuse as Ys

    // carry fragments -> LDS stage (bf16, same precision as before)
#pragma unroll
    for (int nf = 0; nf < 4; ++nf) {
        int l = wn * 64 + nf * 16 + lrow;
#pragma unroll
        for (int mf = 0; mf < 4; ++mf) {
            int rb = wm * 64 + mf * 16 + lk * 4;
#pragma unroll
            for (int r = 0; r < 4; ++r)
                Ys[(rb + r) * 128 + l] = f2bf(acc[mf][nf][r]);
        }
    }
    __syncthreads();

    // fused coalesced epilogue: gbf = bf16(GELU(Ybuf + carry)), short8 rows
    const short8* YsV = (const short8*)Ys;
#pragma unroll
    for (int it = 0; it < 8; ++it) {
        int sidx = it * 256 + tid;          // 0..2047
        int rr = sidx >> 4;                 // local row 0..127
        int colq = sidx & 15;
        int Rr = mh * 128 + rr, bb = Rr >> 4, cc = Rr & 15;
        size_t gaddr = ((size_t)(bb * H_ + h)) * L_ + (size_t)cc * LC_ + colq * 8;
        short8 yv = *(const short8*)(Ybuf + gaddr);
        short8 cv = YsV[sidx];
        short8 o;
#pragma unroll
        for (int j = 0; j < 8; ++j) {
            float y = bf2f((unsigned short)yv[j]) + bf2f((unsigned short)cv[j]);
            o[j] = f2bf(0.5f * y * (1.0f + erff(y * 0.70710678118654752f)));
        }
        *(short8*)(gbf + gaddr) = o;
    }
}

// ---------------------------------------------------------------------------
// W transpose + f32->bf16: Wt[n][k] = bf16(W[k][n])
// ---------------------------------------------------------------------------
__global__ void __launch_bounds__(256)
wtrans(const float* __restrict__ W, short* __restrict__ Wt, int K, int N) {
    __shared__ short tile[32][33];
    int bk = blockIdx.x * 32, bn = blockIdx.y * 32;
    int tx = threadIdx.x & 31, ty = threadIdx.x >> 5;   // ty 0..7
#pragma unroll
    for (int i = 0; i < 4; ++i)
        tile[ty + i * 8][tx] = f2bf(W[(size_t)(bk + ty + i * 8) * N + bn + tx]);
    __syncthreads();
#pragma unroll
    for (int i = 0; i < 4; ++i)
        Wt[(size_t)(bn + ty + i * 8) * K + bk + tx] = tile[tx][ty + i * 8];
}

// ---------------------------------------------------------------------------
// bf16 MFMA GEMM v5 (8 waves / 512 thr / 128x128 tile, DOUBLE-BUFFERED LDS,
// ONE barrier per K-step): C = act(A @ Bt^T + bias). BK=32, wave 64x32,
// acc 4x2. LDS [2][128][36] strided. Per half-iter: issue t+2 global loads
// (statically-named regs, rule #20), MFMA from buf[p], ds_write staged tile
// into buf[p^1], single __syncthreads(). Grid dim3(M/128,N/128): XCD =
// row-panel%8 -> A-panel L2 locality (FETCH 133->33MB, r9-verified).
// Best-known GEMM structure after r15-r17 matrix: gl16 (117), 128x64 (83),
// 256x128 (94) all worse than this (65-68).
// ---------------------------------------------------------------------------
template<bool TANH, bool OUTBF>
__global__ void __launch_bounds__(512)
gemm_mfma(const short* __restrict__ A, const short* __restrict__ Bt,
          const float* __restrict__ bias, void* __restrict__ Cout,
          int M, int N, int K) {
    __shared__ short As[2][128 * 36];
    __shared__ short Bs[2][128 * 36];
    int tid  = threadIdx.x;
    int lane = tid & 63;
    int wave = tid >> 6;                 // 0..7
    int wm = wave >> 2, wn = wave & 3;   // 2M x 4N
    int lrow = lane & 15, kblk = lane >> 4;
    int row0 = blockIdx.x * 128, col0 = blockIdx.y * 128;

    int srow = tid >> 2;            // 0..127
    int sk   = (tid & 3) * 8;       // k offset (shorts)
    const short* Ag = A  + (size_t)(row0 + srow) * K + sk;
    const short* Bg = Bt + (size_t)(col0 + srow) * K + sk;
    int si = srow * 36 + sk;

    f32x4 acc[4][2] = {};
    const int NT = K >> 5;          // 64 (GEMM1) / 32 (GEMM2) — even

    // prologue: tile0 -> buf0; tile1 in flight (statically-named regs)
    short8 pa = *(const short8*)(Ag),      pb = *(const short8*)(Bg);
    *(short8*)&As[0][si] = pa;
    *(short8*)&Bs[0][si] = pb;
    short8 qa = *(const short8*)(Ag + 32), qb = *(const short8*)(Bg + 32);
    __syncthreads();

    for (int t = 0; t < NT; t += 2) {
        // --- half A: compute tile t from buf0; stage tile t+1 -> buf1 ---
        if (t + 2 < NT) {
            int ko = (t + 2) << 5;
            pa = *(const short8*)(Ag + ko);
            pb = *(const short8*)(Bg + ko);
        }
        {
            short8 af[4], bf[2];
#pragma unroll
            for (int m = 0; m < 4; ++m)
                af[m] = *(const short8*)&As[0][(wm * 64 + m * 16 + lrow) * 36 + kblk * 8];
#pragma unroll
            for (int n = 0; n < 2; ++n)
                bf[n] = *(const short8*)&Bs[0][(wn * 32 + n * 16 + lrow) * 36 + kblk * 8];
#pragma unroll
            for (int m = 0; m < 4; ++m)
#pragma unroll
                for (int n = 0; n < 2; ++n)
                    acc[m][n] = __builtin_amdgcn_mfma_f32_16x16x32_bf16(
                        af[m], bf[n], acc[m][n], 0, 0, 0);
        }
        *(short8*)&As[1][si] = qa;
        *(short8*)&Bs[1][si] = qb;
        __syncthreads();

        // --- half B: compute tile t+1 from buf1; stage tile t+2 -> buf0 ---
        if (t + 3 < NT) {
            int ko = (t + 3) << 5;
            qa = *(const short8*)(Ag + ko);
            qb = *(const short8*)(Bg + ko);
        }
        {
            short8 af[4], bf[2];
#pragma unroll
            for (int m = 0; m < 4; ++m)
                af[m] = *(const short8*)&As[1][(wm * 64 + m * 16 + lrow) * 36 + kblk * 8];
#pragma unroll
            for (int n = 0; n < 2; ++n)
                bf[n] = *(const short8*)&Bs[1][(wn * 32 + n * 16 + lrow) * 36 + kblk * 8];
#pragma unroll
            for (int m = 0; m < 4; ++m)
#pragma unroll
                for (int n = 0; n < 2; ++n)
                    acc[m][n] = __builtin_amdgcn_mfma_f32_16x16x32_bf16(
                        af[m], bf[n], acc[m][n], 0, 0, 0);
        }
        if (t + 2 < NT) {
            *(short8*)&As[0][si] = pa;
            *(short8*)&Bs[0][si] = pb;
        }
        __syncthreads();
    }

    // epilogue: C/D layout col=lane&15, row=(lane>>4)*4+reg
#pragma unroll
    for (int n = 0; n < 2; ++n) {
        int col = col0 + wn * 32 + n * 16 + lrow;
        float bb = bias[col];
#pragma unroll
        for (int m = 0; m < 4; ++m) {
            int rowb = row0 + wm * 64 + m * 16 + kblk * 4;
#pragma unroll
            for (int r = 0; r < 4; ++r) {
                float v = acc[m][n][r] + bb;
                if (TANH) v = tanhf(v);
                if (OUTBF) ((short*)Cout)[(size_t)(rowb + r) * N + col] = f2bf(v);
                else       ((float*)Cout)[(size_t)(rowb + r) * N + col] = v;
            }
        }
    }
}

// ---------------------------------------------------------------------------
extern "C" void kernel_launch(void* const* d_in, const int* in_sizes, int n_in,
                              void* d_out, int out_size, void* d_ws, size_t ws_size,
                              hipStream_t stream) {
    const float* u     = (const float*)d_in[0];
    const float* D     = (const float*)d_in[1];
    const float* logdt = (const float*)d_in[2];
    const float* C_re  = (const float*)d_in[3];
    const float* C_im  = (const float*)d_in[4];
    const float* W1    = (const float*)d_in[5];
    const float* b1    = (const float*)d_in[6];
    const float* W2    = (const float*)d_in[7];
    const float* b2    = (const float*)d_in[8];
    float* out = (float*)d_out;

    char* p = (char*)d_ws;
    float4* tab = (float4*)p;            p += 262144;      // H*N2*16
    char* regionA = p;                   p += 33554432;    // POW+ktab, later Ybuf
    float2* POW  = (float2*)regionA;                       // 512*129*32*8
    float*  ktab = (float*)(regionA + 16908288);           // 512*128*4
    short*  Ybuf = (short*)regionA;                        // B*H*L*2 = 32 MB (b,h,l)
    short* Psw = (short*)p;              p += 25165824;    // 512*192*128*2
    short* Vsw = (short*)p;              p += 8388608;     // 512*128*64*2
    float* E   = (float*)p;              p += 33554432;    // 8192*16*64*4
    short* gbf = (short*)p;              p += 33554432;    // B*H*L*2
    short* tb  = (short*)p;              p += 16777216;    // 8192*1024*2
    short* w1t = (short*)p;              p += 4194304;
    short* w2t = (short*)p;

    k0_table<<<H_ * N2_ / 256, 256, 0, stream>>>(logdt, C_re, C_im, tab);
    t0_pow  <<<H_ * N2_ / 256, 256, 0, stream>>>(tab, POW);
    t_ktab  <<<H_ * 128 / 256, 256, 0, stream>>>(tab, POW, D, ktab);
    t1_fill <<<H_ * 320 * 8 / 256, 256, 0, stream>>>(tab, POW, ktab, Psw, Vsw);
    wtrans  <<<dim3(L_ / 32, 2 * H_ / 32), 256, 0, stream>>>(W1, w1t, L_, 2 * H_);
    wtrans  <<<dim3(2 * H_ / 32, H_ / 32), 256, 0, stream>>>(W2, w2t, 2 * H_, H_);

    conv_mfma  <<<H_, 512, 0, stream>>>(u, Psw, E, Ybuf);
    k2_scan    <<<B_ * H_ * N2_ / 256, 256, 0, stream>>>(logdt, (float2*)E);
    dcarry_mfma<<<dim3(H_, 2), 256, 0, stream>>>(E, Vsw, Ybuf, gbf);

    gemm_mfma<true, true ><<<dim3(B_ * H_ / 128, 2 * H_ / 128), 512, 0, stream>>>(
        gbf, w1t, b1, tb, B_ * H_, 2 * H_, L_);
    gemm_mfma<false, false><<<dim3(B_ * H_ / 128, H_ / 128), 512, 0, stream>>>(
        tb, w2t, b2, out, B_ * H_, H_, 2 * H_);
}

// Round 19
// 188.867 us; speedup vs baseline: 1.3571x; 1.0184x over previous
//
#include <hip/hip_runtime.h>
#include <math.h>

#define B_  16
#define H_  512
#define L_  2048
#define N2_ 32
#define NC_ 16
#define LC_ 128   // L_/NC_

typedef __attribute__((ext_vector_type(8))) short short8;
typedef __attribute__((ext_vector_type(4))) float f32x4;

__device__ __forceinline__ short f2bf(float x) {
    unsigned u = __builtin_bit_cast(unsigned, x);
    u += 0x7fffu + ((u >> 16) & 1u);           // round-to-nearest-even
    return (short)(u >> 16);
}
__device__ __forceinline__ float bf2f(unsigned short s) {
    unsigned u = ((unsigned)s) << 16;
    return __builtin_bit_cast(float, u);
}

// ---------------------------------------------------------------------------
// K0: per-(h,n) table: lambda = exp(dt*A), C' = (C_re+iC_im)*(lambda-1)/A
// ---------------------------------------------------------------------------
__global__ void k0_table(const float* __restrict__ log_dt,
                         const float* __restrict__ C_re,
                         const float* __restrict__ C_im,
                         float4* __restrict__ tab) {
    int idx = blockIdx.x * blockDim.x + threadIdx.x;   // h*N2 + n
    if (idx >= H_ * N2_) return;
    int h = idx >> 5, n = idx & 31;
    float dt = expf(log_dt[h]);
    float e  = expf(-0.5f * dt);
    float th = 3.14159265358979323846f * (float)n * dt;
    float lr = e * cosf(th), li = e * sinf(th);
    float ar = -0.5f, ai = 3.14159265358979323846f * (float)n;
    float den = ar * ar + ai * ai;
    float x = lr - 1.0f, y = li;
    float nr = (x * ar + y * ai) / den;
    float ni = (y * ar - x * ai) / den;
    float cr = C_re[idx], ci = C_im[idx];
    tab[idx] = make_float4(lr, li, cr * nr - ci * ni, cr * ni + ci * nr);
}

// ---------------------------------------------------------------------------
// T0 v2: POW[h][m][n] = lambda_n^m, closed-form per element (was a 16K-thread
// serial loop = 64 waves chip-wide, latency-bound ~10us). 2.1M threads,
// contiguous stores. Matches reference's jnp.exp(dtA*l) closed form.
// ---------------------------------------------------------------------------
__global__ void __launch_bounds__(256)
t0_pow(const float* __restrict__ log_dt, float2* __restrict__ POW) {
    int t = blockIdx.x * 256 + threadIdx.x;   // h*129*32 + m*32 + n
    if (t >= H_ * 129 * N2_) return;
    int n = t & 31;
    int m = (t >> 5) % 129;
    int h = t / (129 * N2_);
    float dt = expf(log_dt[h]);
    float fm = (float)m;
    float e  = expf(-0.5f * dt * fm);
    float th = 3.14159265358979323846f * (float)n * dt * fm;
    POW[t] = make_float2(e * cosf(th), e * sinf(th));
}

// ---------------------------------------------------------------------------
// ktab[h][m] = 2 * Re sum_n C'_n * lambda_n^m ; +D[h] at m=0 (folds D*u into
// the Toeplitz diagonal so the GELU stage never touches u).
// ---------------------------------------------------------------------------
__global__ void t_ktab(const float4* __restrict__ tab, const float2* __restrict__ POW,
                       const float* __restrict__ Dv, float* __restrict__ ktab) {
    int t = blockIdx.x * 256 + threadIdx.x;   // h*128 + m
    if (t >= H_ * 128) return;
    int h = t >> 7, m = t & 127;
    const float2* P = POW + (size_t)h * 129 * N2_ + (size_t)m * N2_;
    const float4* tb = tab + h * N2_;
    float s = 0.0f;
    for (int n = 0; n < N2_; ++n) {
        float2 p = P[n];
        float4 v = tb[n];
        s += v.z * p.x - v.w * p.y;
    }
    ktab[t] = 2.0f * s + (m == 0 ? Dv[h] : 0.0f);
}

// ---------------------------------------------------------------------------
// T1: fill Psw (pre-swizzled [h][g16][n192][8] bf16) and Vsw ([h][g8][l128][8]).
// ---------------------------------------------------------------------------
__global__ void __launch_bounds__(256)
t1_fill(const float4* __restrict__ tab, const float2* __restrict__ POW,
        const float* __restrict__ ktab, short* __restrict__ Psw,
        short* __restrict__ Vsw) {
    int t = blockIdx.x * 256 + threadIdx.x;
    int sub = t & 7;
    int rowg = t >> 3;
    int h = rowg / 320, row = rowg % 320;
    if (row < 192) {
        short8 s0, s1;
        if (row < 128) {
            int l = row;
#pragma unroll
            for (int mm = 0; mm < 8; ++mm) {
                int m0 = sub * 16 + mm, m1 = m0 + 8;
                s0[mm] = (m0 <= l) ? f2bf(ktab[h * 128 + (l - m0)]) : (short)0;
                s1[mm] = (m1 <= l) ? f2bf(ktab[h * 128 + (l - m1)]) : (short)0;
            }
        } else {
            int j = row - 128, nn = j >> 1, part = j & 1;
            const float2* P = POW + (size_t)h * 129 * N2_ + nn;
#pragma unroll
            for (int mm = 0; mm < 8; ++mm) {
                int m0 = sub * 16 + mm, m1 = m0 + 8;
                float2 p0 = P[(size_t)(127 - m0) * N2_];
                float2 p1 = P[(size_t)(127 - m1) * N2_];
                s0[mm] = f2bf(part ? p0.y : p0.x);
                s1[mm] = f2bf(part ? p1.y : p1.x);
            }
        }
        *(short8*)(Psw + ((size_t)(h * 16 + sub * 2 + 0) * 192 + row) * 8) = s0;
        *(short8*)(Psw + ((size_t)(h * 16 + sub * 2 + 1) * 192 + row) * 8) = s1;
    } else {
        int l = row - 192;
        const float2* P = POW + (size_t)h * 129 * N2_ + (size_t)(l + 1) * N2_;
        const float4* tb = tab + h * N2_;
        short8 s;
#pragma unroll
        for (int jj = 0; jj < 8; ++jj) {
            int j = sub * 8 + jj, nn = j >> 1;
            float2 p = P[nn];
            float4 cv = tb[nn];
            float re = cv.z * p.x - cv.w * p.y;
            float im = cv.z * p.y + cv.w * p.x;
            s[jj] = f2bf((j & 1) ? -2.0f * im : 2.0f * re);
        }
        *(short8*)(Vsw + ((size_t)(h * 8 + sub) * 128 + l) * 8) = s;
    }
}

// ---------------------------------------------------------------------------
// conv_mfma v3: ONE block per h (512 thr, 8 waves): Out(256x192) =
// U(256x128) @ P_h^T. Y epilogue staged through LDS then written coalesced.
// E (cols 128..191) written direct (64B segments).
// ---------------------------------------------------------------------------
__global__ void __launch_bounds__(512)
conv_mfma(const float* __restrict__ u, const short* __restrict__ Psw,
          float* __restrict__ E, short* __restrict__ Ybuf) {
    __shared__ char smem[65536];
    short* Ps = (short*)smem;                  // [16][192][8] 48K (conv)
    short* As = (short*)(smem + 49152);        // [4][256][8]  16K (conv)
    short* Ys = (short*)smem;                  // [256][128]   64K (post-conv)
    int h = blockIdx.x;
    int tid = threadIdx.x;
    {
        const short8* Pg = (const short8*)(Psw + (size_t)h * 24576);
        short8* PsV = (short8*)Ps;
#pragma unroll
        for (int j = 0; j < 6; ++j) PsV[tid + j * 512] = Pg[tid + j * 512];
    }
    int row = tid >> 1, half = tid & 1;      // row 0..255
    int b0 = row >> 4, c0 = row & 15;
    const float* up = u + ((size_t)(b0 * H_ + h)) * L_ + (size_t)c0 * LC_ + half * 16;
    short8* AsV = (short8*)As;

    int lane = tid & 63, wave = tid >> 6;    // 8 waves
    int wm = wave >> 1, wn = wave & 1;       // 4M x 2N
    int lrow = lane & 15, lk = lane >> 4;
    const short8* AsF = (const short8*)As;
    const short8* PsF = (const short8*)Ps;

    f32x4 acc[4][6] = {};
    float4 fv0 = *(const float4*)(up + 0);
    float4 fv1 = *(const float4*)(up + 4);
    float4 fv2 = *(const float4*)(up + 8);
    float4 fv3 = *(const float4*)(up + 12);
    for (int ks = 0; ks < 4; ++ks) {
        __syncthreads();
        short8 s0, s1;
        s0[0] = f2bf(fv0.x); s0[1] = f2bf(fv0.y); s0[2] = f2bf(fv0.z); s0[3] = f2bf(fv0.w);
        s0[4] = f2bf(fv1.x); s0[5] = f2bf(fv1.y); s0[6] = f2bf(fv1.z); s0[7] = f2bf(fv1.w);
        s1[0] = f2bf(fv2.x); s1[1] = f2bf(fv2.y); s1[2] = f2bf(fv2.z); s1[3] = f2bf(fv2.w);
        s1[4] = f2bf(fv3.x); s1[5] = f2bf(fv3.y); s1[6] = f2bf(fv3.z); s1[7] = f2bf(fv3.w);
        AsV[(half * 2 + 0) * 256 + row] = s0;
        AsV[(half * 2 + 1) * 256 + row] = s1;
        __syncthreads();
        if (ks < 3) {
            const float* nx = up + (ks + 1) * 32;
            fv0 = *(const float4*)(nx + 0);
            fv1 = *(const float4*)(nx + 4);
            fv2 = *(const float4*)(nx + 8);
            fv3 = *(const float4*)(nx + 12);
        }
        short8 af[4], bfr[6];
#pragma unroll
        for (int m = 0; m < 4; ++m)
            af[m] = AsF[lk * 256 + wm * 64 + m * 16 + lrow];
#pragma unroll
        for (int n = 0; n < 6; ++n)
            bfr[n] = PsF[(ks * 4 + lk) * 192 + wn * 96 + n * 16 + lrow];
#pragma unroll
        for (int m = 0; m < 4; ++m)
#pragma unroll
            for (int n = 0; n < 6; ++n)
                acc[m][n] = __builtin_amdgcn_mfma_f32_16x16x32_bf16(
                    af[m], bfr[n], acc[m][n], 0, 0, 0);
    }
    __syncthreads();   // conv LDS reads done; Ps/As reusable as Ys

    // Y fragments -> LDS stage; E fragments -> global direct
#pragma unroll
    for (int nf = 0; nf < 6; ++nf) {
        int col = wn * 96 + nf * 16 + lrow;
#pragma unroll
        for (int mf = 0; mf < 4; ++mf) {
            int rb = wm * 64 + mf * 16 + lk * 4;
#pragma unroll
            for (int r = 0; r < 4; ++r) {
                int Rr = rb + r;
                float vv = acc[mf][nf][r];
                if (col < 128) {
                    Ys[Rr * 128 + col] = f2bf(vv);
                } else {
                    int bb = Rr >> 4, cc = Rr & 15;
                    E[((size_t)(bb * H_ + h) * NC_ + cc) * 64 + (col - 128)] = vv;
                }
            }
        }
    }
    __syncthreads();

    // coalesced copy-out: 16-lane group writes one full 256B Ybuf row
    const short8* YsV = (const short8*)Ys;
#pragma unroll
    for (int it = 0; it < 8; ++it) {
        int sidx = it * 512 + tid;          // short8 index, 0..4095
        int rr = sidx >> 4;                 // local row 0..255
        int colq = sidx & 15;               // short8 within row
        int bb = rr >> 4, cc = rr & 15;
        *(short8*)(Ybuf + ((size_t)(bb * H_ + h)) * L_ + (size_t)cc * LC_ + colq * 8)
            = YsV[sidx];
    }
}

// ---------------------------------------------------------------------------
// K2: per-(b,h,n) serial scan over chunks (exclusive -> S at chunk start).
// ---------------------------------------------------------------------------
__global__ void k2_scan(const float* __restrict__ log_dt, float2* __restrict__ ES) {
    int t = blockIdx.x * 256 + threadIdx.x;
    if (t >= B_ * H_ * N2_) return;
    int n  = t & 31;
    int h  = (t >> 5) & (H_ - 1);
    int bh = t >> 5;
    float dt = expf(log_dt[h]);
    float e  = expf(-0.5f * dt * (float)LC_);
    float th = 3.14159265358979323846f * (float)n * dt * (float)LC_;
    float Lr = e * cosf(th), Li = e * sinf(th);
    float cr = 0.0f, ci = 0.0f;
    float2* base = ES + (size_t)bh * NC_ * N2_ + n;
#pragma unroll
    for (int c = 0; c < NC_; ++c) {
        float2 Ev = base[(size_t)c * N2_];
        base[(size_t)c * N2_] = make_float2(cr, ci);
        float ncr = fmaf(Lr, cr, fmaf(-Li, ci, Ev.x));
        float nci = fmaf(Lr, ci, fmaf(Li, cr, Ev.y));
        cr = ncr; ci = nci;
    }
}

// ---------------------------------------------------------------------------
// dcarry_mfma v2: per (h, mh): Carry(128x128) = S(128x64) @ V_h^T via MFMA.
// Carry fragments staged in LDS (aliasing dead Sa/Vb), then fused coalesced
// epilogue: gbf = bf16(GELU(Ybuf + carry)) in full short8 rows.
// ---------------------------------------------------------------------------
__global__ void __launch_bounds__(256)
dcarry_mfma(const float* __restrict__ ES, const short* __restrict__ Vsw,
            const short* __restrict__ Ybuf, short* __restrict__ gbf) {
    __shared__ char smem[32768];
    short* Sa = (short*)smem;             // [8][128][8] 16 KB
    short* Vb = (short*)(smem + 16384);   // [8][128][8] 16 KB
    short* Ys = (short*)smem;             // [128][128]  32 KB (post-MFMA)
    int h = blockIdx.x, mh = blockIdx.y;
    int tid = threadIdx.x;
    {
        const short8* Vg = (const short8*)(Vsw + (size_t)h * 8192);
        short8* VbV = (short8*)Vb;
#pragma unroll
        for (int j = 0; j < 4; ++j) VbV[tid + j * 256] = Vg[tid + j * 256];
    }
    int row = tid >> 1, half = tid & 1;
    int R = mh * 128 + row, b = R >> 4, c = R & 15;
    {
        const float* sp = ES + ((size_t)(b * H_ + h) * NC_ + c) * 64 + half * 32;
        short8* SaV = (short8*)Sa;
#pragma unroll
        for (int gg = 0; gg < 4; ++gg) {
            float4 f0 = *(const float4*)(sp + gg * 8);
            float4 f1 = *(const float4*)(sp + gg * 8 + 4);
            short8 s;
            s[0] = f2bf(f0.x); s[1] = f2bf(f0.y); s[2] = f2bf(f0.z); s[3] = f2bf(f0.w);
            s[4] = f2bf(f1.x); s[5] = f2bf(f1.y); s[6] = f2bf(f1.z); s[7] = f2bf(f1.w);
            SaV[(half * 4 + gg) * 128 + row] = s;
        }
    }
    __syncthreads();
    int lane = tid & 63, wave = tid >> 6;
    int wm = wave >> 1, wn = wave & 1;
    int lrow = lane & 15, lk = lane >> 4;
    const short8* SaF = (const short8*)Sa;
    const short8* VbF = (const short8*)Vb;
    f32x4 acc[4][4] = {};
#pragma unroll
    for (int ks = 0; ks < 2; ++ks) {
        int g = ks * 4 + lk;
        short8 af[4], bf[4];
#pragma unroll
        for (int m = 0; m < 4; ++m)
            af[m] = SaF[g * 128 + wm * 64 + m * 16 + lrow];
#pragma unroll
        for (int n = 0; n < 4; ++n)
            bf[n] = VbF[g * 128 + wn * 64 + n * 16 + lrow];
#pragma unroll
        for (int m = 0; m < 4; ++m)
#pragma unroll
            for (int n = 0; n < 4; ++n)
                acc[m][n] = __builtin_amdgcn_mfma_f32_16x16x32_bf16(
                    af[m], bf[n], acc[m][n], 0, 0, 0);
    }
    __syncthreads();   // Sa/Vb reads done -> reuse as Ys

    // carry fragments -> LDS stage (bf16, same precision as before)
#pragma unroll
    for (int nf = 0; nf < 4; ++nf) {
        int l = wn * 64 + nf * 16 + lrow;
#pragma unroll
        for (int mf = 0; mf < 4; ++mf) {
            int rb = wm * 64 + mf * 16 + lk * 4;
#pragma unroll
            for (int r = 0; r < 4; ++r)
                Ys[(rb + r) * 128 + l] = f2bf(acc[mf][nf][r]);
        }
    }
    __syncthreads();

    // fused coalesced epilogue: gbf = bf16(GELU(Ybuf + carry)), short8 rows
    const short8* YsV = (const short8*)Ys;
#pragma unroll
    for (int it = 0; it < 8; ++it) {
        int sidx = it * 256 + tid;          // 0..2047
        int rr = sidx >> 4;                 // local row 0..127
        int colq = sidx & 15;
        int Rr = mh * 128 + rr, bb = Rr >> 4, cc = Rr & 15;
        size_t gaddr = ((size_t)(bb * H_ + h)) * L_ + (size_t)cc * LC_ + colq * 8;
        short8 yv = *(const short8*)(Ybuf + gaddr);
        short8 cv = YsV[sidx];
        short8 o;
#pragma unroll
        for (int j = 0; j < 8; ++j) {
            float y = bf2f((unsigned short)yv[j]) + bf2f((unsigned short)cv[j]);
            o[j] = f2bf(0.5f * y * (1.0f + erff(y * 0.70710678118654752f)));
        }
        *(short8*)(gbf + gaddr) = o;
    }
}

// ---------------------------------------------------------------------------
// W transpose + f32->bf16: Wt[n][k] = bf16(W[k][n])
// ---------------------------------------------------------------------------
__global__ void __launch_bounds__(256)
wtrans(const float* __restrict__ W, short* __restrict__ Wt, int K, int N) {
    __shared__ short tile[32][33];
    int bk = blockIdx.x * 32, bn = blockIdx.y * 32;
    int tx = threadIdx.x & 31, ty = threadIdx.x >> 5;   // ty 0..7
#pragma unroll
    for (int i = 0; i < 4; ++i)
        tile[ty + i * 8][tx] = f2bf(W[(size_t)(bk + ty + i * 8) * N + bn + tx]);
    __syncthreads();
#pragma unroll
    for (int i = 0; i < 4; ++i)
        Wt[(size_t)(bn + ty + i * 8) * K + bk + tx] = tile[tx][ty + i * 8];
}

// ---------------------------------------------------------------------------
// bf16 MFMA GEMM v5+T5 (8 waves / 512 thr / 128x128 tile, dbuf LDS, one
// barrier per K-step, s_setprio(1) around the MFMA clusters — v5's dbuf
// schedule has compute-vs-stage wave role split, the regime where T5 pays).
// Grid dim3(M/128,N/128): XCD = row-panel%8 -> A-panel L2 locality.
// ---------------------------------------------------------------------------
template<bool TANH, bool OUTBF>
__global__ void __launch_bounds__(512)
gemm_mfma(const short* __restrict__ A, const short* __restrict__ Bt,
          const float* __restrict__ bias, void* __restrict__ Cout,
          int M, int N, int K) {
    __shared__ short As[2][128 * 36];
    __shared__ short Bs[2][128 * 36];
    int tid  = threadIdx.x;
    int lane = tid & 63;
    int wave = tid >> 6;                 // 0..7
    int wm = wave >> 2, wn = wave & 3;   // 2M x 4N
    int lrow = lane & 15, kblk = lane >> 4;
    int row0 = blockIdx.x * 128, col0 = blockIdx.y * 128;

    int srow = tid >> 2;            // 0..127
    int sk   = (tid & 3) * 8;       // k offset (shorts)
    const short* Ag = A  + (size_t)(row0 + srow) * K + sk;
    const short* Bg = Bt + (size_t)(col0 + srow) * K + sk;
    int si = srow * 36 + sk;

    f32x4 acc[4][2] = {};
    const int NT = K >> 5;          // 64 (GEMM1) / 32 (GEMM2) — even

    short8 pa = *(const short8*)(Ag),      pb = *(const short8*)(Bg);
    *(short8*)&As[0][si] = pa;
    *(short8*)&Bs[0][si] = pb;
    short8 qa = *(const short8*)(Ag + 32), qb = *(const short8*)(Bg + 32);
    __syncthreads();

    for (int t = 0; t < NT; t += 2) {
        if (t + 2 < NT) {
            int ko = (t + 2) << 5;
            pa = *(const short8*)(Ag + ko);
            pb = *(const short8*)(Bg + ko);
        }
        {
            short8 af[4], bf[2];
#pragma unroll
            for (int m = 0; m < 4; ++m)
                af[m] = *(const short8*)&As[0][(wm * 64 + m * 16 + lrow) * 36 + kblk * 8];
#pragma unroll
            for (int n = 0; n < 2; ++n)
                bf[n] = *(const short8*)&Bs[0][(wn * 32 + n * 16 + lrow) * 36 + kblk * 8];
            __builtin_amdgcn_s_setprio(1);
#pragma unroll
            for (int m = 0; m < 4; ++m)
#pragma unroll
                for (int n = 0; n < 2; ++n)
                    acc[m][n] = __builtin_amdgcn_mfma_f32_16x16x32_bf16(
                        af[m], bf[n], acc[m][n], 0, 0, 0);
            __builtin_amdgcn_s_setprio(0);
        }
        *(short8*)&As[1][si] = qa;
        *(short8*)&Bs[1][si] = qb;
        __syncthreads();

        if (t + 3 < NT) {
            int ko = (t + 3) << 5;
            qa = *(const short8*)(Ag + ko);
            qb = *(const short8*)(Bg + ko);
        }
        {
            short8 af[4], bf[2];
#pragma unroll
            for (int m = 0; m < 4; ++m)
                af[m] = *(const short8*)&As[1][(wm * 64 + m * 16 + lrow) * 36 + kblk * 8];
#pragma unroll
            for (int n = 0; n < 2; ++n)
                bf[n] = *(const short8*)&Bs[1][(wn * 32 + n * 16 + lrow) * 36 + kblk * 8];
            __builtin_amdgcn_s_setprio(1);
#pragma unroll
            for (int m = 0; m < 4; ++m)
#pragma unroll
                for (int n = 0; n < 2; ++n)
                    acc[m][n] = __builtin_amdgcn_mfma_f32_16x16x32_bf16(
                        af[m], bf[n], acc[m][n], 0, 0, 0);
            __builtin_amdgcn_s_setprio(0);
        }
        if (t + 2 < NT) {
            *(short8*)&As[0][si] = pa;
            *(short8*)&Bs[0][si] = pb;
        }
        __syncthreads();
    }

    // epilogue: C/D layout col=lane&15, row=(lane>>4)*4+reg
#pragma unroll
    for (int n = 0; n < 2; ++n) {
        int col = col0 + wn * 32 + n * 16 + lrow;
        float bb = bias[col];
#pragma unroll
        for (int m = 0; m < 4; ++m) {
            int rowb = row0 + wm * 64 + m * 16 + kblk * 4;
#pragma unroll
            for (int r = 0; r < 4; ++r) {
                float v = acc[m][n][r] + bb;
                if (TANH) v = tanhf(v);
                if (OUTBF) ((short*)Cout)[(size_t)(rowb + r) * N + col] = f2bf(v);
                else       ((float*)Cout)[(size_t)(rowb + r) * N + col] = v;
            }
        }
    }
}

// ---------------------------------------------------------------------------
extern "C" void kernel_launch(void* const* d_in, const int* in_sizes, int n_in,
                              void* d_out, int out_size, void* d_ws, size_t ws_size,
                              hipStream_t stream) {
    const float* u     = (const float*)d_in[0];
    const float* D     = (const float*)d_in[1];
    const float* logdt = (const float*)d_in[2];
    const float* C_re  = (const float*)d_in[3];
    const float* C_im  = (const float*)d_in[4];
    const float* W1    = (const float*)d_in[5];
    const float* b1    = (const float*)d_in[6];
    const float* W2    = (const float*)d_in[7];
    const float* b2    = (const float*)d_in[8];
    float* out = (float*)d_out;

    char* p = (char*)d_ws;
    float4* tab = (float4*)p;            p += 262144;      // H*N2*16
    char* regionA = p;                   p += 33554432;    // POW+ktab, later Ybuf
    float2* POW  = (float2*)regionA;                       // 512*129*32*8
    float*  ktab = (float*)(regionA + 16908288);           // 512*128*4
    short*  Ybuf = (short*)regionA;                        // B*H*L*2 = 32 MB (b,h,l)
    short* Psw = (short*)p;              p += 25165824;    // 512*192*128*2
    short* Vsw = (short*)p;              p += 8388608;     // 512*128*64*2
    float* E   = (float*)p;              p += 33554432;    // 8192*16*64*4
    short* gbf = (short*)p;              p += 33554432;    // B*H*L*2
    short* tb  = (short*)p;              p += 16777216;    // 8192*1024*2
    short* w1t = (short*)p;              p += 4194304;
    short* w2t = (short*)p;

    k0_table<<<H_ * N2_ / 256, 256, 0, stream>>>(logdt, C_re, C_im, tab);
    t0_pow  <<<H_ * 129 * N2_ / 256, 256, 0, stream>>>(logdt, POW);
    t_ktab  <<<H_ * 128 / 256, 256, 0, stream>>>(tab, POW, D, ktab);
    t1_fill <<<H_ * 320 * 8 / 256, 256, 0, stream>>>(tab, POW, ktab, Psw, Vsw);
    wtrans  <<<dim3(L_ / 32, 2 * H_ / 32), 256, 0, stream>>>(W1, w1t, L_, 2 * H_);
    wtrans  <<<dim3(2 * H_ / 32, H_ / 32), 256, 0, stream>>>(W2, w2t, 2 * H_, H_);

    conv_mfma  <<<H_, 512, 0, stream>>>(u, Psw, E, Ybuf);
    k2_scan    <<<B_ * H_ * N2_ / 256, 256, 0, stream>>>(logdt, (float2*)E);
    dcarry_mfma<<<dim3(H_, 2), 256, 0, stream>>>(E, Vsw, Ybuf, gbf);

    gemm_mfma<true, true ><<<dim3(B_ * H_ / 128, 2 * H_ / 128), 512, 0, stream>>>(
        gbf, w1t, b1, tb, B_ * H_, 2 * H_, L_);
    gemm_mfma<false, false><<<dim3(B_ * H_ / 128, H_ / 128), 512, 0, stream>>>(
        tb, w2t, b2, out, B_ * H_, H_, 2 * H_);
}